// Round 1
// baseline (395.771 us; speedup 1.0000x reference)
//
#include <hip/hip_runtime.h>
#include <math.h>

#define B_ 2
#define T_ 1024
#define C_ 1024
#define NH 16
#define DH 64
#define M_ 128
#define LCH 64
#define NC (T_/LCH)          // 16 chunks
#define TC3 (3*C_)

constexpr float SCALE = 0.125f;              // 1/sqrt(64)
constexpr float EPSV = 1e-6f;
constexpr float INV_SQRT_M = 0.088388347648318447f;  // 1/sqrt(128)

// ---------------- generic fp32 tiled GEMM with bias: C = A(MxK) @ B(KxN) + bias ----------------
__global__ __launch_bounds__(256) void gemm_bias_kernel(
    const float* __restrict__ A, const float* __restrict__ Bm,
    const float* __restrict__ bias, float* __restrict__ Cm,
    int M, int N, int K) {
  __shared__ float As[16][68];   // [k][m], padded
  __shared__ float Bs[16][68];   // [k][n], padded
  int tid = threadIdx.x;
  int bm = blockIdx.y * 64, bn = blockIdx.x * 64;
  int ty = tid >> 4, tx = tid & 15;
  int arow = tid >> 2, ak4 = (tid & 3) * 4;
  int brow = tid >> 4, bc4 = (tid & 15) * 4;
  float acc[4][4] = {};
  for (int kt = 0; kt < K; kt += 16) {
    float4 a4 = *(const float4*)&A[(size_t)(bm + arow) * K + kt + ak4];
    float4 b4 = *(const float4*)&Bm[(size_t)(kt + brow) * N + bn + bc4];
    __syncthreads();
    As[ak4 + 0][arow] = a4.x; As[ak4 + 1][arow] = a4.y;
    As[ak4 + 2][arow] = a4.z; As[ak4 + 3][arow] = a4.w;
    *(float4*)&Bs[brow][bc4] = b4;
    __syncthreads();
#pragma unroll
    for (int k = 0; k < 16; ++k) {
      float4 av = *(float4*)&As[k][ty * 4];
      float4 bv = *(float4*)&Bs[k][tx * 4];
      float aa[4] = {av.x, av.y, av.z, av.w};
      float bb[4] = {bv.x, bv.y, bv.z, bv.w};
#pragma unroll
      for (int i = 0; i < 4; ++i)
#pragma unroll
        for (int j = 0; j < 4; ++j) acc[i][j] += aa[i] * bb[j];
    }
  }
#pragma unroll
  for (int i = 0; i < 4; ++i) {
    float4 o;
    o.x = acc[i][0] + bias[bn + tx * 4 + 0];
    o.y = acc[i][1] + bias[bn + tx * 4 + 1];
    o.z = acc[i][2] + bias[bn + tx * 4 + 2];
    o.w = acc[i][3] + bias[bn + tx * 4 + 3];
    *(float4*)&Cm[(size_t)(bm + ty * 4 + i) * N + bn + tx * 4] = o;
  }
}

// ---------------- phi kernel: phi = exp(q_scaled @ omega - 0.5||q_scaled||^2)/sqrt(m) ----------
__global__ __launch_bounds__(256) void phi_kernel(const float* __restrict__ qkv,
                                                  const float* __restrict__ omega,
                                                  float* __restrict__ phi_q,
                                                  float* __restrict__ phi_k) {
  __shared__ float om_s[DH * M_];   // 32 KB
  __shared__ float qk_s[2 * DH];
  int tid = threadIdx.x;
  int bh = blockIdx.x;              // b*NH + h
  int b = bh / NH, h = bh % NH;
  int t0 = blockIdx.y * 32;
  for (int e = tid * 4; e < DH * M_; e += 256 * 4)
    *(float4*)&om_s[e] = *(const float4*)&omega[e];
  int mi = tid & (M_ - 1);
  int isK = tid >> 7;               // wave-uniform
  float* dst = (isK ? phi_k : phi_q) + (size_t)bh * T_ * M_;
  for (int tt = 0; tt < 32; ++tt) {
    int t = t0 + tt;
    __syncthreads();
    if (tid < 128) {
      int j = tid;
      size_t off = (size_t)b * T_ * TC3 + (size_t)t * TC3 + h * DH +
                   (j < DH ? j : C_ + (j - DH));
      qk_s[j] = qkv[off] * SCALE;
    }
    __syncthreads();
    const float* qp = &qk_s[isK * DH];
    float proj = 0.f, nsq = 0.f;
#pragma unroll 8
    for (int d = 0; d < DH; ++d) {
      float qv = qp[d];
      proj += qv * om_s[d * M_ + mi];
      nsq += qv * qv;
    }
    dst[((size_t)t) * M_ + mi] = __expf(proj - 0.5f * nsq) * INV_SQRT_M;
  }
}

// ---------------- per-chunk sums: S_c = phi_k_chunk^T @ v_chunk (m x d), z_c = sum phi_k -------
__global__ __launch_bounds__(256) void chunk_sum_kernel(const float* __restrict__ qkv,
                                                        const float* __restrict__ phi_k,
                                                        float* __restrict__ S,
                                                        float* __restrict__ Z) {
  __shared__ float pk_s[8 * M_];
  __shared__ float v_s[8 * DH];
  int tid = threadIdx.x;
  int bc = blockIdx.x;              // bh*NC + c
  int bh = bc / NC, c = bc % NC;
  int b = bh / NH, h = bh % NH;
  int tbase = c * LCH;
  float acc[32];
#pragma unroll
  for (int i = 0; i < 32; ++i) acc[i] = 0.f;
  int di = tid & 63;
  int mibase = (tid >> 6) * 32;     // wave-uniform
  for (int t0 = 0; t0 < LCH; t0 += 8) {
    __syncthreads();
    { int e = tid * 4;
      *(float4*)&pk_s[e] = *(const float4*)&phi_k[((size_t)bh * T_ + tbase + t0) * M_ + e]; }
    if (tid < 128) {
      int tt = tid >> 4, d4 = (tid & 15) * 4;
      *(float4*)&v_s[tt * DH + d4] = *(const float4*)&qkv[(size_t)b * T_ * TC3 +
          (size_t)(tbase + t0 + tt) * TC3 + 2 * C_ + h * DH + d4];
    }
    __syncthreads();
#pragma unroll
    for (int tt = 0; tt < 8; ++tt) {
      float vv = v_s[tt * DH + di];
      const float* pk = &pk_s[tt * M_ + mibase];
#pragma unroll
      for (int i = 0; i < 32; ++i) acc[i] += pk[i] * vv;
    }
  }
  float* Sdst = S + (size_t)bc * (M_ * DH);
#pragma unroll
  for (int i = 0; i < 32; ++i) Sdst[(mibase + i) * DH + di] = acc[i];
  if (tid < M_) {
    float z = 0.f;
    for (int tl = 0; tl < LCH; ++tl)
      z += phi_k[((size_t)bh * T_ + tbase + tl) * M_ + tid];
    Z[(size_t)bc * M_ + tid] = z;
  }
}

// ---------------- exclusive prefix over chunks (per head) -------------------------------------
__global__ __launch_bounds__(256) void prefix_kernel(float* __restrict__ S, float* __restrict__ Z) {
  int bh = blockIdx.x;
  int tid = threadIdx.x;
  float run[32];
#pragma unroll
  for (int j = 0; j < 32; ++j) run[j] = 0.f;
  size_t base = (size_t)bh * NC * (M_ * DH);
  for (int c = 0; c < NC; ++c) {
    float* p = S + base + (size_t)c * (M_ * DH);
#pragma unroll
    for (int j = 0; j < 32; ++j) {
      int e = tid + j * 256;
      float tmp = p[e];
      p[e] = run[j];
      run[j] += tmp;
    }
  }
  if (tid < M_) {
    float rz = 0.f;
    float* zp = Z + (size_t)bh * NC * M_;
    for (int c = 0; c < NC; ++c) {
      float tmp = zp[c * M_ + tid];
      zp[c * M_ + tid] = rz;
      rz += tmp;
    }
  }
}

// ---------------- intra-chunk: A = causal(phi_q phi_k^T); y = (A@v + phi_q@Sprev)/den ---------
__global__ __launch_bounds__(256) void intra_kernel(const float* __restrict__ qkv,
    const float* __restrict__ phi_q, const float* __restrict__ phi_k,
    const float* __restrict__ S, const float* __restrict__ Z,
    float* __restrict__ y) {
  __shared__ float pq_s[M_ * 68];   // [mi][ti]
  __shared__ float bufB[M_ * 68];   // phi_k [mi][tj], then Sprev [mi][di]
  __shared__ float v_s[LCH * 68];   // [tj][di]
  __shared__ float A_s[LCH * 65];   // [ti][tj]
  __shared__ float den_s[LCH];
  int tid = threadIdx.x;
  int bc = blockIdx.x;
  int bh = bc / NC, c = bc % NC;
  int b = bh / NH, h = bh % NH;
  int tbase = c * LCH;
  // stage phi_q / phi_k transposed to [mi][t]
  const float* pqg = &phi_q[((size_t)bh * T_ + tbase) * M_];
  const float* pkg = &phi_k[((size_t)bh * T_ + tbase) * M_];
#pragma unroll
  for (int pass = 0; pass < 8; ++pass) {
    int e = pass * 1024 + tid * 4;
    int row = e >> 7, mi = e & 127;
    float4 q4 = *(const float4*)&pqg[e];
    float4 k4 = *(const float4*)&pkg[e];
    pq_s[(mi + 0) * 68 + row] = q4.x; pq_s[(mi + 1) * 68 + row] = q4.y;
    pq_s[(mi + 2) * 68 + row] = q4.z; pq_s[(mi + 3) * 68 + row] = q4.w;
    bufB[(mi + 0) * 68 + row] = k4.x; bufB[(mi + 1) * 68 + row] = k4.y;
    bufB[(mi + 2) * 68 + row] = k4.z; bufB[(mi + 3) * 68 + row] = k4.w;
  }
#pragma unroll
  for (int pass = 0; pass < 4; ++pass) {
    int e = pass * 1024 + tid * 4;
    int row = e >> 6, d4 = e & 63;
    *(float4*)&v_s[row * 68 + d4] = *(const float4*)&qkv[(size_t)b * T_ * TC3 +
        (size_t)(tbase + row) * TC3 + 2 * C_ + h * DH + d4];
  }
  __syncthreads();
  // A phase: 4x4 microtile per thread over 128-deep dot
  int ty = tid >> 4, tx = tid & 15;
  int ti0 = ty * 4, tj0 = tx * 4;
  float accA[4][4] = {};
  for (int mi = 0; mi < M_; ++mi) {
    float4 aq = *(float4*)&pq_s[mi * 68 + ti0];
    float4 bk = *(float4*)&bufB[mi * 68 + tj0];
    float aa[4] = {aq.x, aq.y, aq.z, aq.w};
    float bb[4] = {bk.x, bk.y, bk.z, bk.w};
#pragma unroll
    for (int i = 0; i < 4; ++i)
#pragma unroll
      for (int j = 0; j < 4; ++j) accA[i][j] += aa[i] * bb[j];
  }
#pragma unroll
  for (int i = 0; i < 4; ++i)
#pragma unroll
    for (int j = 0; j < 4; ++j)
      A_s[(ti0 + i) * 65 + tj0 + j] = (tj0 + j <= ti0 + i) ? accA[i][j] : 0.f;
  __syncthreads();
  // overwrite bufB with Sprev; threads<64 compute den
  const float* Sp = S + (size_t)bc * (M_ * DH);
#pragma unroll
  for (int pass = 0; pass < 8; ++pass) {
    int e = pass * 1024 + tid * 4;
    int mi = e >> 6, d4 = e & 63;
    *(float4*)&bufB[mi * 68 + d4] = *(const float4*)&Sp[e];
  }
  if (tid < LCH) {
    int ti = tid;
    float dsum = EPSV;
    for (int tj = 0; tj <= ti; ++tj) dsum += A_s[ti * 65 + tj];
    const float* Zp = Z + (size_t)bc * M_;
    float zd = 0.f;
    for (int mi = 0; mi < M_; ++mi) zd += pq_s[mi * 68 + ti] * Zp[mi];
    den_s[ti] = dsum + zd;
  }
  __syncthreads();
  // phase B: each thread owns (ti, 16 d-values)
  int ti = tid >> 2, d0 = (tid & 3) * 16;
  float accn[16] = {};
  for (int tj = 0; tj < LCH; ++tj) {
    float a = A_s[ti * 65 + tj];
    const float* vp = &v_s[tj * 68 + d0];
#pragma unroll
    for (int i = 0; i < 16; ++i) accn[i] += a * vp[i];
  }
  for (int mi = 0; mi < M_; ++mi) {
    float pq = pq_s[mi * 68 + ti];
    const float* sp = &bufB[mi * 68 + d0];
#pragma unroll
    for (int i = 0; i < 16; ++i) accn[i] += pq * sp[i];
  }
  float invd = 1.0f / den_s[ti];
  float* yp = y + (size_t)b * T_ * C_ + (size_t)(tbase + ti) * C_ + h * DH + d0;
#pragma unroll
  for (int i = 0; i < 16; i += 4) {
    float4 o;
    o.x = accn[i + 0] * invd; o.y = accn[i + 1] * invd;
    o.z = accn[i + 2] * invd; o.w = accn[i + 3] * invd;
    *(float4*)&yp[i] = o;
  }
}

extern "C" void kernel_launch(void* const* d_in, const int* in_sizes, int n_in,
                              void* d_out, int out_size, void* d_ws, size_t ws_size,
                              hipStream_t stream) {
  const float* x      = (const float*)d_in[0];
  const float* W_attn = (const float*)d_in[1];
  const float* b_attn = (const float*)d_in[2];
  const float* W_proj = (const float*)d_in[3];
  const float* b_proj = (const float*)d_in[4];
  const float* omega  = (const float*)d_in[5];
  float* out = (float*)d_out;

  float* ws = (float*)d_ws;
  float* qkv   = ws;                                        // 6,291,456
  float* phi_q = qkv   + (size_t)B_ * T_ * TC3;             // 4,194,304
  float* phi_k = phi_q + (size_t)B_ * NH * T_ * M_;         // 4,194,304
  float* S     = phi_k + (size_t)B_ * NH * T_ * M_;         // 4,194,304
  float* Z     = S     + (size_t)B_ * NH * NC * M_ * DH;    // 65,536
  float* y     = Z     + (size_t)B_ * NH * NC * M_;         // 2,097,152

  // 1. qkv = x @ W_attn + b_attn    (2048 x 3072 x 1024)
  gemm_bias_kernel<<<dim3(TC3 / 64, (B_ * T_) / 64), 256, 0, stream>>>(
      x, W_attn, b_attn, qkv, B_ * T_, TC3, C_);
  // 2. phi features
  phi_kernel<<<dim3(B_ * NH, T_ / 32), 256, 0, stream>>>(qkv, omega, phi_q, phi_k);
  // 3. per-chunk state sums
  chunk_sum_kernel<<<B_ * NH * NC, 256, 0, stream>>>(qkv, phi_k, S, Z);
  // 4. exclusive prefix over chunks
  prefix_kernel<<<B_ * NH, 256, 0, stream>>>(S, Z);
  // 5. intra-chunk + cross-chunk combine
  intra_kernel<<<B_ * NH * NC, 256, 0, stream>>>(qkv, phi_q, phi_k, S, Z, y);
  // 6. out = y @ W_proj + b_proj   (2048 x 1024 x 1024)
  gemm_bias_kernel<<<dim3(C_ / 64, (B_ * T_) / 64), 256, 0, stream>>>(
      y, W_proj, b_proj, out, B_ * T_, C_, C_);
}

// Round 2
// 229.736 us; speedup vs baseline: 1.7227x; 1.7227x over previous
//
#include <hip/hip_runtime.h>
#include <math.h>

#define B_ 2
#define T_ 1024
#define C_ 1024
#define NH 16
#define DH 64
#define M_ 128
#define LCH 64
#define NC (T_/LCH)          // 16 chunks

constexpr float SCALE = 0.125f;              // 1/sqrt(64)
constexpr float EPSV = 1e-6f;
constexpr float INV_SQRT_M = 0.088388347648318447f;  // 1/sqrt(128)

typedef unsigned short u16;
typedef short bf16x8 __attribute__((ext_vector_type(8)));
typedef float f32x4 __attribute__((ext_vector_type(4)));
typedef u16 u16x4 __attribute__((ext_vector_type(4)));
typedef u16 u16x8 __attribute__((ext_vector_type(8)));

typedef const __attribute__((address_space(1))) void* as1_cvoid_p;
typedef __attribute__((address_space(3))) void* as3_void_p;

__device__ __forceinline__ void gload16(const void* g, void* l) {
  __builtin_amdgcn_global_load_lds((as1_cvoid_p)g, (as3_void_p)l, 16, 0, 0);
}

__device__ __forceinline__ u16 f2bf(float f) {
  union { float f; unsigned u; } x; x.f = f;
  unsigned r = x.u + 0x7fffu + ((x.u >> 16) & 1u);
  return (u16)(r >> 16);
}
__device__ __forceinline__ float bf2f(u16 h) {
  union { unsigned u; float f; } x; x.u = ((unsigned)h) << 16;
  return x.f;
}

// ---------- split fp32 row-major (2048x1024) -> bf16 [m][hi(0..1024)|lo(1024..2048)] ----------
__global__ __launch_bounds__(256) void split_rm_kernel(const float* __restrict__ in,
                                                       u16* __restrict__ out) {
  int i = (blockIdx.x * 256 + threadIdx.x) * 4;   // total 2048*1024
  float4 v = *(const float4*)&in[i];
  int m = i >> 10, k = i & 1023;
  u16 h0 = f2bf(v.x), h1 = f2bf(v.y), h2 = f2bf(v.z), h3 = f2bf(v.w);
  u16x4 hv = {h0, h1, h2, h3};
  u16x4 lv = {f2bf(v.x - bf2f(h0)), f2bf(v.y - bf2f(h1)),
              f2bf(v.z - bf2f(h2)), f2bf(v.w - bf2f(h3))};
  size_t ob = (size_t)m * 2048 + k;
  *(u16x4*)&out[ob] = hv;
  *(u16x4*)&out[ob + 1024] = lv;
}

// ---------- split+transpose fp32 W (K x N) -> bf16 out[n][hi k | lo k] (n-major, 2K cols) -----
__global__ __launch_bounds__(256) void split_tr_kernel(const float* __restrict__ in,
                                                       u16* __restrict__ out, int K, int N) {
  __shared__ float tile[32][33];
  int tid = threadIdx.x;
  int n0 = blockIdx.x * 32, k0 = blockIdx.y * 32;
  int tx = tid & 31, ty = tid >> 5;
  for (int r = ty; r < 32; r += 8)
    tile[r][tx] = in[(size_t)(k0 + r) * N + n0 + tx];
  __syncthreads();
  for (int r = ty; r < 32; r += 8) {
    float v = tile[tx][r];
    u16 hv = f2bf(v);
    u16 lv = f2bf(v - bf2f(hv));
    size_t ob = (size_t)(n0 + r) * (2 * K) + k0 + tx;
    out[ob] = hv;
    out[ob + K] = lv;
  }
}

// ---------- split-bf16 MFMA GEMM: C = A(2048 x fp32-K1024) @ B(K x N) + bias -------------------
// A2: [row][2048] bf16 = [hi|lo]; B2: [n][2048] bf16 = [hi|lo] (B^T). K' = 3072 via slice map.
template <int BM, int BN, bool SPLITC>
__global__ __launch_bounds__(256) void gemm_split_kernel(
    const u16* __restrict__ A2, const u16* __restrict__ B2,
    const float* __restrict__ bias, float* __restrict__ C0, float* __restrict__ C1,
    int csplit, int ldc0, int ldc1) {
  constexpr int MI = BM / 32, NI = BN / 32;
  __shared__ u16 As[BM * 32];
  __shared__ u16 Bs[BN * 32];
  const int tid = threadIdx.x;
  const int wid = tid >> 6, lane = tid & 63;
  const int bm = blockIdx.y * BM, bn = blockIdx.x * BN;
  const int wr = (wid >> 1) * (BM / 2), wc = (wid & 1) * (BN / 2);
  const int sr = wid * 16 + (lane >> 2), sk = (lane & 3) * 8;
  const int frow = lane & 15, fk = (lane >> 4) * 8;
  f32x4 acc[MI][NI];
#pragma unroll
  for (int mi = 0; mi < MI; ++mi)
#pragma unroll
    for (int ni = 0; ni < NI; ++ni) acc[mi][ni] = f32x4{0.f, 0.f, 0.f, 0.f};

  for (int kt = 0; kt < 3072; kt += 32) {
    const int kta = kt < 1024 ? kt : kt - 1024;
    const int ktb = kt < 2048 ? kt : kt - 2048;
    __syncthreads();
#pragma unroll
    for (int i = 0; i < BM / 64; ++i)
      gload16(&A2[(size_t)(bm + i * 64 + sr) * 2048 + kta + sk],
              (char*)As + i * 4096 + wid * 1024);
#pragma unroll
    for (int i = 0; i < BN / 64; ++i)
      gload16(&B2[(size_t)(bn + i * 64 + sr) * 2048 + ktb + sk],
              (char*)Bs + i * 4096 + wid * 1024);
    __syncthreads();
    bf16x8 af[MI], bfv[NI];
#pragma unroll
    for (int mi = 0; mi < MI; ++mi)
      af[mi] = *(const bf16x8*)&As[(wr + mi * 16 + frow) * 32 + fk];
#pragma unroll
    for (int ni = 0; ni < NI; ++ni)
      bfv[ni] = *(const bf16x8*)&Bs[(wc + ni * 16 + frow) * 32 + fk];
#pragma unroll
    for (int mi = 0; mi < MI; ++mi)
#pragma unroll
      for (int ni = 0; ni < NI; ++ni)
        acc[mi][ni] = __builtin_amdgcn_mfma_f32_16x16x32_bf16(af[mi], bfv[ni], acc[mi][ni], 0, 0, 0);
  }
#pragma unroll
  for (int ni = 0; ni < NI; ++ni) {
    int col = bn + wc + ni * 16 + frow;
    float bv = bias[col];
    float* base = (SPLITC && col >= csplit) ? C1 : C0;
    int ld = (SPLITC && col >= csplit) ? ldc1 : ldc0;
    int cc = (SPLITC && col >= csplit) ? col - csplit : col;
#pragma unroll
    for (int mi = 0; mi < MI; ++mi) {
      int row0 = bm + wr + mi * 16 + (lane >> 4) * 4;
#pragma unroll
      for (int r = 0; r < 4; ++r)
        base[(size_t)(row0 + r) * ld + cc] = acc[mi][ni][r] + bv;
    }
  }
}

// ---------- phi: GEMM-shaped, per block: one (bh, 64-t tile, q-or-k) --------------------------
__global__ __launch_bounds__(256) void phi_kernel(const float* __restrict__ qk,
                                                  const float* __restrict__ omega,
                                                  float* __restrict__ phi_q,
                                                  float* __restrict__ phi_k) {
  __shared__ float om_s[DH][M_ + 4];
  __shared__ float q_s[DH][72];
  __shared__ float nsq_s[64];
  int tid = threadIdx.x;
  int bh = blockIdx.x, tc = blockIdx.y, isK = blockIdx.z;
  int b = bh >> 4, h = bh & 15;
  int t0 = tc * 64;
  for (int e = tid * 4; e < DH * M_; e += 1024) {
    int d = e >> 7, m = e & 127;
    *(float4*)&om_s[d][m] = *(const float4*)&omega[e];
  }
  {
    int c4 = (tid & 15) * 4;
    for (int row = tid >> 4; row < 64; row += 16) {
      float4 v = *(const float4*)&qk[(size_t)(b * T_ + t0 + row) * 2048 + isK * 1024 + h * DH + c4];
      q_s[c4 + 0][row] = v.x; q_s[c4 + 1][row] = v.y;
      q_s[c4 + 2][row] = v.z; q_s[c4 + 3][row] = v.w;
    }
  }
  __syncthreads();
  if (tid < 64) {
    float s = 0.f;
#pragma unroll
    for (int d = 0; d < DH; ++d) { float v = q_s[d][tid]; s += v * v; }
    nsq_s[tid] = s;
  }
  __syncthreads();
  int ti0 = (tid >> 4) * 4, mj0 = (tid & 15) * 8;
  float acc[4][8] = {};
  for (int d = 0; d < DH; ++d) {
    float a0 = q_s[d][ti0 + 0], a1 = q_s[d][ti0 + 1];
    float a2 = q_s[d][ti0 + 2], a3 = q_s[d][ti0 + 3];
    float4 b0 = *(float4*)&om_s[d][mj0];
    float4 b1 = *(float4*)&om_s[d][mj0 + 4];
    float bb[8] = {b0.x, b0.y, b0.z, b0.w, b1.x, b1.y, b1.z, b1.w};
#pragma unroll
    for (int j = 0; j < 8; ++j) {
      acc[0][j] += a0 * bb[j]; acc[1][j] += a1 * bb[j];
      acc[2][j] += a2 * bb[j]; acc[3][j] += a3 * bb[j];
    }
  }
  float* dst = (isK ? phi_k : phi_q) + (size_t)bh * T_ * M_;
#pragma unroll
  for (int i = 0; i < 4; ++i) {
    float nh_ = -0.5f * SCALE * SCALE * nsq_s[ti0 + i];
    float4 o0, o1;
    o0.x = __expf(SCALE * acc[i][0] + nh_) * INV_SQRT_M;
    o0.y = __expf(SCALE * acc[i][1] + nh_) * INV_SQRT_M;
    o0.z = __expf(SCALE * acc[i][2] + nh_) * INV_SQRT_M;
    o0.w = __expf(SCALE * acc[i][3] + nh_) * INV_SQRT_M;
    o1.x = __expf(SCALE * acc[i][4] + nh_) * INV_SQRT_M;
    o1.y = __expf(SCALE * acc[i][5] + nh_) * INV_SQRT_M;
    o1.z = __expf(SCALE * acc[i][6] + nh_) * INV_SQRT_M;
    o1.w = __expf(SCALE * acc[i][7] + nh_) * INV_SQRT_M;
    float* dp = dst + (size_t)(t0 + ti0 + i) * M_ + mj0;
    *(float4*)dp = o0;
    *(float4*)(dp + 4) = o1;
  }
}

// ---------- per-chunk sums: S_c = phi_k_chunk^T @ v_chunk (m x d), z_c = sum phi_k -------------
__global__ __launch_bounds__(256) void chunk_sum_kernel(const float* __restrict__ v,
                                                        const float* __restrict__ phi_k,
                                                        float* __restrict__ S,
                                                        float* __restrict__ Z) {
  __shared__ float pk_s[8 * M_];
  __shared__ float v_s[8 * DH];
  int tid = threadIdx.x;
  int bc = blockIdx.x;
  int bh = bc / NC, c = bc % NC;
  int b = bh / NH, h = bh % NH;
  int tbase = c * LCH;
  float acc[32];
#pragma unroll
  for (int i = 0; i < 32; ++i) acc[i] = 0.f;
  int di = tid & 63;
  int mibase = (tid >> 6) * 32;
  for (int t0 = 0; t0 < LCH; t0 += 8) {
    __syncthreads();
    { int e = tid * 4;
      *(float4*)&pk_s[e] = *(const float4*)&phi_k[((size_t)bh * T_ + tbase + t0) * M_ + e]; }
    if (tid < 128) {
      int tt = tid >> 4, d4 = (tid & 15) * 4;
      *(float4*)&v_s[tt * DH + d4] = *(const float4*)&v[(size_t)(b * T_ + tbase + t0 + tt) * C_ + h * DH + d4];
    }
    __syncthreads();
#pragma unroll
    for (int tt = 0; tt < 8; ++tt) {
      float vv = v_s[tt * DH + di];
      const float* pk = &pk_s[tt * M_ + mibase];
#pragma unroll
      for (int i = 0; i < 32; ++i) acc[i] += pk[i] * vv;
    }
  }
  float* Sdst = S + (size_t)bc * (M_ * DH);
#pragma unroll
  for (int i = 0; i < 32; ++i) Sdst[(mibase + i) * DH + di] = acc[i];
  if (tid < M_) {
    float z = 0.f;
    for (int tl = 0; tl < LCH; ++tl)
      z += phi_k[((size_t)bh * T_ + tbase + tl) * M_ + tid];
    Z[(size_t)bc * M_ + tid] = z;
  }
}

// ---------- exclusive prefix over chunks, parallel over (bh, m-group) -------------------------
__global__ __launch_bounds__(256) void prefix_kernel(float* __restrict__ S, float* __restrict__ Z) {
  int tid = threadIdx.x;
  int bh = blockIdx.x, mg = blockIdx.y;
  int m = mg * 16 + (tid >> 4), d4 = (tid & 15) * 4;
  size_t off = (size_t)bh * NC * (M_ * DH) + (size_t)m * DH + d4;
  float4 run = {0.f, 0.f, 0.f, 0.f};
  for (int c = 0; c < NC; ++c) {
    float* p = &S[off + (size_t)c * (M_ * DH)];
    float4 val = *(float4*)p;
    *(float4*)p = run;
    run.x += val.x; run.y += val.y; run.z += val.z; run.w += val.w;
  }
  if (mg == 0 && tid < M_) {
    float rz = 0.f;
    float* zp = Z + (size_t)bh * NC * M_;
    for (int c = 0; c < NC; ++c) {
      float tmp = zp[c * M_ + tid];
      zp[c * M_ + tid] = rz;
      rz += tmp;
    }
  }
}

// ---------- intra-chunk + cross-chunk combine; emits y as bf16 hi/lo split --------------------
__global__ __launch_bounds__(256) void intra_kernel(const float* __restrict__ v,
    const float* __restrict__ phi_q, const float* __restrict__ phi_k,
    const float* __restrict__ S, const float* __restrict__ Z,
    u16* __restrict__ y2) {
  __shared__ float pq_s[M_ * 68];
  __shared__ float bufB[M_ * 68];
  __shared__ float v_s[LCH * 68];
  __shared__ float A_s[LCH * 65];
  __shared__ float den_s[LCH];
  int tid = threadIdx.x;
  int bc = blockIdx.x;
  int bh = bc / NC, c = bc % NC;
  int b = bh / NH, h = bh % NH;
  int tbase = c * LCH;
  const float* pqg = &phi_q[((size_t)bh * T_ + tbase) * M_];
  const float* pkg = &phi_k[((size_t)bh * T_ + tbase) * M_];
#pragma unroll
  for (int pass = 0; pass < 8; ++pass) {
    int e = pass * 1024 + tid * 4;
    int row = e >> 7, mi = e & 127;
    float4 q4 = *(const float4*)&pqg[e];
    float4 k4 = *(const float4*)&pkg[e];
    pq_s[(mi + 0) * 68 + row] = q4.x; pq_s[(mi + 1) * 68 + row] = q4.y;
    pq_s[(mi + 2) * 68 + row] = q4.z; pq_s[(mi + 3) * 68 + row] = q4.w;
    bufB[(mi + 0) * 68 + row] = k4.x; bufB[(mi + 1) * 68 + row] = k4.y;
    bufB[(mi + 2) * 68 + row] = k4.z; bufB[(mi + 3) * 68 + row] = k4.w;
  }
#pragma unroll
  for (int pass = 0; pass < 4; ++pass) {
    int e = pass * 1024 + tid * 4;
    int row = e >> 6, d4 = e & 63;
    *(float4*)&v_s[row * 68 + d4] = *(const float4*)&v[(size_t)(b * T_ + tbase + row) * C_ + h * DH + d4];
  }
  __syncthreads();
  int ty = tid >> 4, tx = tid & 15;
  int ti0 = ty * 4, tj0 = tx * 4;
  float accA[4][4] = {};
  for (int mi = 0; mi < M_; ++mi) {
    float4 aq = *(float4*)&pq_s[mi * 68 + ti0];
    float4 bk = *(float4*)&bufB[mi * 68 + tj0];
    float aa[4] = {aq.x, aq.y, aq.z, aq.w};
    float bb[4] = {bk.x, bk.y, bk.z, bk.w};
#pragma unroll
    for (int i = 0; i < 4; ++i)
#pragma unroll
      for (int j = 0; j < 4; ++j) accA[i][j] += aa[i] * bb[j];
  }
#pragma unroll
  for (int i = 0; i < 4; ++i)
#pragma unroll
    for (int j = 0; j < 4; ++j)
      A_s[(ti0 + i) * 65 + tj0 + j] = (tj0 + j <= ti0 + i) ? accA[i][j] : 0.f;
  __syncthreads();
  const float* Sp = S + (size_t)bc * (M_ * DH);
#pragma unroll
  for (int pass = 0; pass < 8; ++pass) {
    int e = pass * 1024 + tid * 4;
    int mi = e >> 6, d4 = e & 63;
    *(float4*)&bufB[mi * 68 + d4] = *(const float4*)&Sp[e];
  }
  if (tid < LCH) {
    int ti = tid;
    float dsum = EPSV;
    for (int tj = 0; tj <= ti; ++tj) dsum += A_s[ti * 65 + tj];
    const float* Zp = Z + (size_t)bc * M_;
    float zd = 0.f;
    for (int mi = 0; mi < M_; ++mi) zd += pq_s[mi * 68 + ti] * Zp[mi];
    den_s[ti] = dsum + zd;
  }
  __syncthreads();
  int ti = tid >> 2, d0 = (tid & 3) * 16;
  float accn[16] = {};
  for (int tj = 0; tj < LCH; ++tj) {
    float a = A_s[ti * 65 + tj];
    const float* vp = &v_s[tj * 68 + d0];
#pragma unroll
    for (int i = 0; i < 16; ++i) accn[i] += a * vp[i];
  }
  for (int mi = 0; mi < M_; ++mi) {
    float pq = pq_s[mi * 68 + ti];
    const float* sp = &bufB[mi * 68 + d0];
#pragma unroll
    for (int i = 0; i < 16; ++i) accn[i] += pq * sp[i];
  }
  float invd = 1.0f / den_s[ti];
  u16x8 hv[2], lv[2];
#pragma unroll
  for (int i = 0; i < 16; ++i) {
    float o = accn[i] * invd;
    u16 h_ = f2bf(o);
    hv[i >> 3][i & 7] = h_;
    lv[i >> 3][i & 7] = f2bf(o - bf2f(h_));
  }
  int grow = b * T_ + tbase + ti;
  u16* yp = y2 + (size_t)grow * 2048 + h * DH + d0;
  *(u16x8*)yp = hv[0];
  *(u16x8*)(yp + 8) = hv[1];
  *(u16x8*)(yp + 1024) = lv[0];
  *(u16x8*)(yp + 1032) = lv[1];
}

extern "C" void kernel_launch(void* const* d_in, const int* in_sizes, int n_in,
                              void* d_out, int out_size, void* d_ws, size_t ws_size,
                              hipStream_t stream) {
  const float* x      = (const float*)d_in[0];
  const float* W_attn = (const float*)d_in[1];
  const float* b_attn = (const float*)d_in[2];
  const float* W_proj = (const float*)d_in[3];
  const float* b_proj = (const float*)d_in[4];
  const float* omega  = (const float*)d_in[5];
  float* out = (float*)d_out;

  float* ws    = (float*)d_ws;
  float* qk    = ws;                          // 4,194,304 f32 (q|k cols)   [S aliases later]
  float* v     = qk + 4194304;                // 2,097,152 f32
  float* phi_q = v + 2097152;                 // 4,194,304 f32
  float* phi_k = phi_q + 4194304;             // 4,194,304 f32
  float* Z     = phi_k + 4194304;             // 65,536 f32
  u16*   A2    = (u16*)(Z + 65536);           // 4,194,304 u16 (x split)    [y2 aliases later]
  u16*   B2    = (u16*)((float*)(void*)A2 + 2097152);  // 6,291,456 u16 (W split, B^T)
  float* S     = qk;                          // alias: qk dead after phi
  u16*   y2    = A2;                          // alias: A2 dead after gemm1

  // 1. split x -> A2 (hi|lo), W_attn -> B2 (transposed hi|lo)
  split_rm_kernel<<<2048, 256, 0, stream>>>(x, A2);
  split_tr_kernel<<<dim3(96, 32), 256, 0, stream>>>(W_attn, B2, 1024, 3072);
  // 2. qkv GEMM (split-C: cols<2048 -> qk, cols>=2048 -> v)
  gemm_split_kernel<128, 64, true><<<dim3(48, 16), 256, 0, stream>>>(
      A2, B2, b_attn, qk, v, 2048, 2048, 1024);
  // 3. W_proj split (reuses B2; safe after gemm1)
  split_tr_kernel<<<dim3(32, 32), 256, 0, stream>>>(W_proj, B2, 1024, 1024);
  // 4. phi features
  phi_kernel<<<dim3(32, 16, 2), 256, 0, stream>>>(qk, omega, phi_q, phi_k);
  // 5. per-chunk state sums (S overwrites qk region — qk no longer needed)
  chunk_sum_kernel<<<B_ * NH * NC, 256, 0, stream>>>(v, phi_k, S, Z);
  // 6. exclusive prefix over chunks
  prefix_kernel<<<dim3(32, 8), 256, 0, stream>>>(S, Z);
  // 7. intra-chunk + cross-chunk combine -> y2 (bf16 hi|lo, overwrites A2)
  intra_kernel<<<B_ * NH * NC, 256, 0, stream>>>(v, phi_q, phi_k, S, Z, y2);
  // 8. out = y @ W_proj + b_proj
  gemm_split_kernel<64, 64, false><<<dim3(16, 32), 256, 0, stream>>>(
      y2, B2, b_proj, out, nullptr, 1 << 30, 1024, 0);
}

// Round 3
// 162.275 us; speedup vs baseline: 2.4389x; 1.4157x over previous
//
#include <hip/hip_runtime.h>
#include <math.h>

#define B_ 2
#define T_ 1024
#define C_ 1024
#define NH 16
#define DH 64
#define M_ 128
#define LCH 64
#define NC (T_/LCH)          // 16 chunks

constexpr float SCALE = 0.125f;              // 1/sqrt(64)
constexpr float EPSV = 1e-6f;
constexpr float INV_SQRT_M = 0.088388347648318447f;  // 1/sqrt(128)

typedef _Float16 f16;
typedef f16 f16x4 __attribute__((ext_vector_type(4)));
typedef f16 f16x8 __attribute__((ext_vector_type(8)));
typedef float f32x4 __attribute__((ext_vector_type(4)));

typedef const __attribute__((address_space(1))) void* as1_cvoid_p;
typedef __attribute__((address_space(3))) void* as3_void_p;

__device__ __forceinline__ void gload16(const void* g, void* l) {
  __builtin_amdgcn_global_load_lds((as1_cvoid_p)g, (as3_void_p)l, 16, 0, 0);
}

// ---------- convert fp32 row-major (2048x1024) -> fp16 same layout ----------------------------
__global__ __launch_bounds__(256) void conv16_kernel(const float* __restrict__ in,
                                                     f16* __restrict__ out) {
  int i = (blockIdx.x * 256 + threadIdx.x) * 4;
  float4 v = *(const float4*)&in[i];
  f16x4 o = {(f16)v.x, (f16)v.y, (f16)v.z, (f16)v.w};
  *(f16x4*)&out[i] = o;
}

// ---------- transpose fp32 W (K x N) -> fp16 out[n][K] (n-major) ------------------------------
__global__ __launch_bounds__(256) void tr16_kernel(const float* __restrict__ in,
                                                   f16* __restrict__ out, int K, int N) {
  __shared__ float tile[32][33];
  int tid = threadIdx.x;
  int n0 = blockIdx.x * 32, k0 = blockIdx.y * 32;
  int tx = tid & 31, ty = tid >> 5;
  for (int r = ty; r < 32; r += 8)
    tile[r][tx] = in[(size_t)(k0 + r) * N + n0 + tx];
  __syncthreads();
  for (int r = ty; r < 32; r += 8)
    out[(size_t)(n0 + r) * K + k0 + tx] = (f16)tile[tx][r];
}

// ---------- fp16 MFMA GEMM: C = A(M x K) @ B^T(N x K) + bias ----------------------------------
template <int BM, int BN, bool SPLITC>
__global__ __launch_bounds__(256) void gemm_f16_kernel(
    const f16* __restrict__ A, const f16* __restrict__ B,
    const float* __restrict__ bias, float* __restrict__ C0, float* __restrict__ C1,
    int csplit, int ldc0, int ldc1, int K) {
  constexpr int MI = BM / 32, NI = BN / 32;
  __shared__ f16 As[BM * 32];
  __shared__ f16 Bs[BN * 32];
  const int tid = threadIdx.x;
  const int wid = tid >> 6, lane = tid & 63;
  const int bm = blockIdx.y * BM, bn = blockIdx.x * BN;
  const int wr = (wid >> 1) * (BM / 2), wc = (wid & 1) * (BN / 2);
  const int sr = wid * 16 + (lane >> 2), sk = (lane & 3) * 8;
  const int frow = lane & 15, fk = (lane >> 4) * 8;
  f32x4 acc[MI][NI];
#pragma unroll
  for (int mi = 0; mi < MI; ++mi)
#pragma unroll
    for (int ni = 0; ni < NI; ++ni) acc[mi][ni] = f32x4{0.f, 0.f, 0.f, 0.f};

  for (int kt = 0; kt < K; kt += 32) {
    __syncthreads();
#pragma unroll
    for (int i = 0; i < BM / 64; ++i)
      gload16(&A[(size_t)(bm + i * 64 + sr) * K + kt + sk],
              (char*)As + i * 4096 + wid * 1024);
#pragma unroll
    for (int i = 0; i < BN / 64; ++i)
      gload16(&B[(size_t)(bn + i * 64 + sr) * K + kt + sk],
              (char*)Bs + i * 4096 + wid * 1024);
    __syncthreads();
    f16x8 af[MI], bfv[NI];
#pragma unroll
    for (int mi = 0; mi < MI; ++mi)
      af[mi] = *(const f16x8*)&As[(wr + mi * 16 + frow) * 32 + fk];
#pragma unroll
    for (int ni = 0; ni < NI; ++ni)
      bfv[ni] = *(const f16x8*)&Bs[(wc + ni * 16 + frow) * 32 + fk];
#pragma unroll
    for (int mi = 0; mi < MI; ++mi)
#pragma unroll
      for (int ni = 0; ni < NI; ++ni)
        acc[mi][ni] = __builtin_amdgcn_mfma_f32_16x16x32_f16(af[mi], bfv[ni], acc[mi][ni], 0, 0, 0);
  }
#pragma unroll
  for (int ni = 0; ni < NI; ++ni) {
    int col = bn + wc + ni * 16 + frow;
    float bv = bias[col];
    float* base = (SPLITC && col >= csplit) ? C1 : C0;
    int ld = (SPLITC && col >= csplit) ? ldc1 : ldc0;
    int cc = (SPLITC && col >= csplit) ? col - csplit : col;
#pragma unroll
    for (int mi = 0; mi < MI; ++mi) {
      int row0 = bm + wr + mi * 16 + (lane >> 4) * 4;
#pragma unroll
      for (int r = 0; r < 4; ++r)
        base[(size_t)(row0 + r) * ld + cc] = acc[mi][ni][r] + bv;
    }
  }
}

// ---------- phi: GEMM-shaped, per block: one (bh, 64-t tile, q-or-k) --------------------------
__global__ __launch_bounds__(256) void phi_kernel(const float* __restrict__ qk,
                                                  const float* __restrict__ omega,
                                                  float* __restrict__ phi_q,
                                                  float* __restrict__ phi_k) {
  __shared__ float om_s[DH][M_ + 4];
  __shared__ float q_s[DH][72];
  __shared__ float nsq_s[64];
  int tid = threadIdx.x;
  int bh = blockIdx.x, tc = blockIdx.y, isK = blockIdx.z;
  int b = bh >> 4, h = bh & 15;
  int t0 = tc * 64;
  for (int e = tid * 4; e < DH * M_; e += 1024) {
    int d = e >> 7, m = e & 127;
    *(float4*)&om_s[d][m] = *(const float4*)&omega[e];
  }
  {
    int c4 = (tid & 15) * 4;
    for (int row = tid >> 4; row < 64; row += 16) {
      float4 v = *(const float4*)&qk[(size_t)(b * T_ + t0 + row) * 2048 + isK * 1024 + h * DH + c4];
      q_s[c4 + 0][row] = v.x; q_s[c4 + 1][row] = v.y;
      q_s[c4 + 2][row] = v.z; q_s[c4 + 3][row] = v.w;
    }
  }
  __syncthreads();
  if (tid < 64) {
    float s = 0.f;
#pragma unroll
    for (int d = 0; d < DH; ++d) { float v = q_s[d][tid]; s += v * v; }
    nsq_s[tid] = s;
  }
  __syncthreads();
  int ti0 = (tid >> 4) * 4, mj0 = (tid & 15) * 8;
  float acc[4][8] = {};
  for (int d = 0; d < DH; ++d) {
    float a0 = q_s[d][ti0 + 0], a1 = q_s[d][ti0 + 1];
    float a2 = q_s[d][ti0 + 2], a3 = q_s[d][ti0 + 3];
    float4 b0 = *(float4*)&om_s[d][mj0];
    float4 b1 = *(float4*)&om_s[d][mj0 + 4];
    float bb[8] = {b0.x, b0.y, b0.z, b0.w, b1.x, b1.y, b1.z, b1.w};
#pragma unroll
    for (int j = 0; j < 8; ++j) {
      acc[0][j] += a0 * bb[j]; acc[1][j] += a1 * bb[j];
      acc[2][j] += a2 * bb[j]; acc[3][j] += a3 * bb[j];
    }
  }
  float* dst = (isK ? phi_k : phi_q) + (size_t)bh * T_ * M_;
#pragma unroll
  for (int i = 0; i < 4; ++i) {
    float nh_ = -0.5f * SCALE * SCALE * nsq_s[ti0 + i];
    float4 o0, o1;
    o0.x = __expf(SCALE * acc[i][0] + nh_) * INV_SQRT_M;
    o0.y = __expf(SCALE * acc[i][1] + nh_) * INV_SQRT_M;
    o0.z = __expf(SCALE * acc[i][2] + nh_) * INV_SQRT_M;
    o0.w = __expf(SCALE * acc[i][3] + nh_) * INV_SQRT_M;
    o1.x = __expf(SCALE * acc[i][4] + nh_) * INV_SQRT_M;
    o1.y = __expf(SCALE * acc[i][5] + nh_) * INV_SQRT_M;
    o1.z = __expf(SCALE * acc[i][6] + nh_) * INV_SQRT_M;
    o1.w = __expf(SCALE * acc[i][7] + nh_) * INV_SQRT_M;
    float* dp = dst + (size_t)(t0 + ti0 + i) * M_ + mj0;
    *(float4*)dp = o0;
    *(float4*)(dp + 4) = o1;
  }
}

// ---------- per-chunk sums: S_c = phi_k_chunk^T @ v_chunk (m x d), z_c = sum phi_k -------------
__global__ __launch_bounds__(256) void chunk_sum_kernel(const float* __restrict__ v,
                                                        const float* __restrict__ phi_k,
                                                        float* __restrict__ S,
                                                        float* __restrict__ Z) {
  __shared__ float pk_s[8 * M_];
  __shared__ float v_s[8 * DH];
  int tid = threadIdx.x;
  int bc = blockIdx.x;
  int bh = bc / NC, c = bc % NC;
  int b = bh / NH, h = bh % NH;
  int tbase = c * LCH;
  float acc[32];
#pragma unroll
  for (int i = 0; i < 32; ++i) acc[i] = 0.f;
  int di = tid & 63;
  int mibase = (tid >> 6) * 32;
  for (int t0 = 0; t0 < LCH; t0 += 8) {
    __syncthreads();
    { int e = tid * 4;
      *(float4*)&pk_s[e] = *(const float4*)&phi_k[((size_t)bh * T_ + tbase + t0) * M_ + e]; }
    if (tid < 128) {
      int tt = tid >> 4, d4 = (tid & 15) * 4;
      *(float4*)&v_s[tt * DH + d4] = *(const float4*)&v[(size_t)(b * T_ + tbase + t0 + tt) * C_ + h * DH + d4];
    }
    __syncthreads();
#pragma unroll
    for (int tt = 0; tt < 8; ++tt) {
      float vv = v_s[tt * DH + di];
      const float* pk = &pk_s[tt * M_ + mibase];
#pragma unroll
      for (int i = 0; i < 32; ++i) acc[i] += pk[i] * vv;
    }
  }
  float* Sdst = S + (size_t)bc * (M_ * DH);
#pragma unroll
  for (int i = 0; i < 32; ++i) Sdst[(mibase + i) * DH + di] = acc[i];
  if (tid < M_) {
    float z = 0.f;
    for (int tl = 0; tl < LCH; ++tl)
      z += phi_k[((size_t)bh * T_ + tbase + tl) * M_ + tid];
    Z[(size_t)bc * M_ + tid] = z;
  }
}

// ---------- exclusive prefix over chunks, parallel over (bh, m-group) -------------------------
__global__ __launch_bounds__(256) void prefix_kernel(float* __restrict__ S, float* __restrict__ Z) {
  int tid = threadIdx.x;
  int bh = blockIdx.x, mg = blockIdx.y;
  int m = mg * 16 + (tid >> 4), d4 = (tid & 15) * 4;
  size_t off = (size_t)bh * NC * (M_ * DH) + (size_t)m * DH + d4;
  float4 run = {0.f, 0.f, 0.f, 0.f};
  for (int c = 0; c < NC; ++c) {
    float* p = &S[off + (size_t)c * (M_ * DH)];
    float4 val = *(float4*)p;
    *(float4*)p = run;
    run.x += val.x; run.y += val.y; run.z += val.z; run.w += val.w;
  }
  if (mg == 0 && tid < M_) {
    float rz = 0.f;
    float* zp = Z + (size_t)bh * NC * M_;
    for (int c = 0; c < NC; ++c) {
      float tmp = zp[c * M_ + tid];
      zp[c * M_ + tid] = rz;
      rz += tmp;
    }
  }
}

// ---------- intra-chunk + cross-chunk combine; emits y as fp16 --------------------------------
__global__ __launch_bounds__(256) void intra_kernel(const float* __restrict__ v,
    const float* __restrict__ phi_q, const float* __restrict__ phi_k,
    const float* __restrict__ S, const float* __restrict__ Z,
    f16* __restrict__ y16) {
  __shared__ float pq_s[M_ * 68];
  __shared__ float bufB[M_ * 68];
  __shared__ float v_s[LCH * 68];
  __shared__ float A_s[LCH * 65];
  __shared__ float den_s[LCH];
  int tid = threadIdx.x;
  int bc = blockIdx.x;
  int bh = bc / NC, c = bc % NC;
  int b = bh / NH, h = bh % NH;
  int tbase = c * LCH;
  const float* pqg = &phi_q[((size_t)bh * T_ + tbase) * M_];
  const float* pkg = &phi_k[((size_t)bh * T_ + tbase) * M_];
#pragma unroll
  for (int pass = 0; pass < 8; ++pass) {
    int e = pass * 1024 + tid * 4;
    int row = e >> 7, mi = e & 127;
    float4 q4 = *(const float4*)&pqg[e];
    float4 k4 = *(const float4*)&pkg[e];
    pq_s[(mi + 0) * 68 + row] = q4.x; pq_s[(mi + 1) * 68 + row] = q4.y;
    pq_s[(mi + 2) * 68 + row] = q4.z; pq_s[(mi + 3) * 68 + row] = q4.w;
    bufB[(mi + 0) * 68 + row] = k4.x; bufB[(mi + 1) * 68 + row] = k4.y;
    bufB[(mi + 2) * 68 + row] = k4.z; bufB[(mi + 3) * 68 + row] = k4.w;
  }
#pragma unroll
  for (int pass = 0; pass < 4; ++pass) {
    int e = pass * 1024 + tid * 4;
    int row = e >> 6, d4 = e & 63;
    *(float4*)&v_s[row * 68 + d4] = *(const float4*)&v[(size_t)(b * T_ + tbase + row) * C_ + h * DH + d4];
  }
  __syncthreads();
  int ty = tid >> 4, tx = tid & 15;
  int ti0 = ty * 4, tj0 = tx * 4;
  float accA[4][4] = {};
  for (int mi = 0; mi < M_; ++mi) {
    float4 aq = *(float4*)&pq_s[mi * 68 + ti0];
    float4 bk = *(float4*)&bufB[mi * 68 + tj0];
    float aa[4] = {aq.x, aq.y, aq.z, aq.w};
    float bb[4] = {bk.x, bk.y, bk.z, bk.w};
#pragma unroll
    for (int i = 0; i < 4; ++i)
#pragma unroll
      for (int j = 0; j < 4; ++j) accA[i][j] += aa[i] * bb[j];
  }
#pragma unroll
  for (int i = 0; i < 4; ++i)
#pragma unroll
    for (int j = 0; j < 4; ++j)
      A_s[(ti0 + i) * 65 + tj0 + j] = (tj0 + j <= ti0 + i) ? accA[i][j] : 0.f;
  __syncthreads();
  const float* Sp = S + (size_t)bc * (M_ * DH);
#pragma unroll
  for (int pass = 0; pass < 8; ++pass) {
    int e = pass * 1024 + tid * 4;
    int mi = e >> 6, d4 = e & 63;
    *(float4*)&bufB[mi * 68 + d4] = *(const float4*)&Sp[e];
  }
  if (tid < LCH) {
    int ti = tid;
    float dsum = EPSV;
    for (int tj = 0; tj <= ti; ++tj) dsum += A_s[ti * 65 + tj];
    const float* Zp = Z + (size_t)bc * M_;
    float zd = 0.f;
    for (int mi = 0; mi < M_; ++mi) zd += pq_s[mi * 68 + ti] * Zp[mi];
    den_s[ti] = dsum + zd;
  }
  __syncthreads();
  int ti = tid >> 2, d0 = (tid & 3) * 16;
  float accn[16] = {};
  for (int tj = 0; tj < LCH; ++tj) {
    float a = A_s[ti * 65 + tj];
    const float* vp = &v_s[tj * 68 + d0];
#pragma unroll
    for (int i = 0; i < 16; ++i) accn[i] += a * vp[i];
  }
  for (int mi = 0; mi < M_; ++mi) {
    float pq = pq_s[mi * 68 + ti];
    const float* sp = &bufB[mi * 68 + d0];
#pragma unroll
    for (int i = 0; i < 16; ++i) accn[i] += pq * sp[i];
  }
  float invd = 1.0f / den_s[ti];
  f16x8 o0, o1;
#pragma unroll
  for (int i = 0; i < 8; ++i) {
    o0[i] = (f16)(accn[i] * invd);
    o1[i] = (f16)(accn[i + 8] * invd);
  }
  int grow = b * T_ + tbase + ti;
  f16* yp = y16 + (size_t)grow * 1024 + h * DH + d0;
  *(f16x8*)yp = o0;
  *(f16x8*)(yp + 8) = o1;
}

extern "C" void kernel_launch(void* const* d_in, const int* in_sizes, int n_in,
                              void* d_out, int out_size, void* d_ws, size_t ws_size,
                              hipStream_t stream) {
  const float* x      = (const float*)d_in[0];
  const float* W_attn = (const float*)d_in[1];
  const float* b_attn = (const float*)d_in[2];
  const float* W_proj = (const float*)d_in[3];
  const float* b_proj = (const float*)d_in[4];
  const float* omega  = (const float*)d_in[5];
  float* out = (float*)d_out;

  float* ws    = (float*)d_ws;
  float* qk    = ws;                          // 4,194,304 f32 (q|k cols)   [S aliases later]
  float* v     = qk + 4194304;                // 2,097,152 f32
  float* phi_q = v + 2097152;                 // 4,194,304 f32
  float* phi_k = phi_q + 4194304;             // 4,194,304 f32
  float* Z     = phi_k + 4194304;             // 65,536 f32
  f16*   A16   = (f16*)(Z + 65536);           // 2,097,152 f16 (x as fp16)  [y16 aliases later]
  f16*   B16   = A16 + 2097152;               // 3,145,728 f16 (W^T fp16)
  float* S     = qk;                          // alias: qk dead after phi
  f16*   y16   = A16;                         // alias: A16 dead after gemm1

  // 1. convert x -> fp16; W_attn -> transposed fp16
  conv16_kernel<<<2048, 256, 0, stream>>>(x, A16);
  tr16_kernel<<<dim3(96, 32), 256, 0, stream>>>(W_attn, B16, 1024, 3072);
  // 2. qkv GEMM (split-C: cols<2048 -> qk, cols>=2048 -> v)
  gemm_f16_kernel<128, 64, true><<<dim3(48, 16), 256, 0, stream>>>(
      A16, B16, b_attn, qk, v, 2048, 2048, 1024, 1024);
  // 3. W_proj transpose (reuses B16; safe after gemm1)
  tr16_kernel<<<dim3(32, 32), 256, 0, stream>>>(W_proj, B16, 1024, 1024);
  // 4. phi features
  phi_kernel<<<dim3(32, 16, 2), 256, 0, stream>>>(qk, omega, phi_q, phi_k);
  // 5. per-chunk state sums (S overwrites qk region — qk no longer needed)
  chunk_sum_kernel<<<B_ * NH * NC, 256, 0, stream>>>(v, phi_k, S, Z);
  // 6. exclusive prefix over chunks
  prefix_kernel<<<dim3(32, 8), 256, 0, stream>>>(S, Z);
  // 7. intra-chunk + cross-chunk combine -> y16 (fp16, overwrites A16)
  intra_kernel<<<B_ * NH * NC, 256, 0, stream>>>(v, phi_q, phi_k, S, Z, y16);
  // 8. out = y @ W_proj + b_proj
  gemm_f16_kernel<64, 64, false><<<dim3(16, 32), 256, 0, stream>>>(
      y16, B16, b_proj, out, nullptr, 1 << 30, 1024, 0, 1024);
}

// Round 4
// 99.650 us; speedup vs baseline: 3.9716x; 1.6285x over previous
//
#include <hip/hip_runtime.h>
#include <math.h>

#define B_ 2
#define T_ 1024
#define C_ 1024
#define NH 16
#define DH 64
#define M_ 128
#define LCH 64
#define NC (T_/LCH)          // 16 chunks
#define DEXT 80              // 64 d + den-row(64) + pad

constexpr float SCALE = 0.125f;              // 1/sqrt(64)
constexpr float EPSV = 1e-6f;
constexpr float INV_SQRT_M = 0.088388347648318447f;  // 1/sqrt(128)

typedef _Float16 f16;
typedef f16 f16x4 __attribute__((ext_vector_type(4)));
typedef f16 f16x8 __attribute__((ext_vector_type(8)));
typedef float f32x4 __attribute__((ext_vector_type(4)));

typedef const __attribute__((address_space(1))) void* as1_cvoid_p;
typedef __attribute__((address_space(3))) void* as3_void_p;

__device__ __forceinline__ void gload16(const void* g, void* l) {
  __builtin_amdgcn_global_load_lds((as1_cvoid_p)g, (as3_void_p)l, 16, 0, 0);
}

// ---------- convert fp32 row-major (2048x1024) -> fp16 same layout ----------------------------
__global__ __launch_bounds__(256) void conv16_kernel(const float* __restrict__ in,
                                                     f16* __restrict__ out) {
  int i = (blockIdx.x * 256 + threadIdx.x) * 4;
  float4 v = *(const float4*)&in[i];
  f16x4 o = {(f16)v.x, (f16)v.y, (f16)v.z, (f16)v.w};
  *(f16x4*)&out[i] = o;
}

// ---------- transpose fp32 W (K x N) -> fp16 out[n][K] ----------------------------------------
__global__ __launch_bounds__(256) void tr16_kernel(const float* __restrict__ in,
                                                   f16* __restrict__ out, int K, int N) {
  __shared__ float tile[32][33];
  int tid = threadIdx.x;
  int n0 = blockIdx.x * 32, k0 = blockIdx.y * 32;
  int tx = tid & 31, ty = tid >> 5;
  for (int r = ty; r < 32; r += 8)
    tile[r][tx] = in[(size_t)(k0 + r) * N + n0 + tx];
  __syncthreads();
  for (int r = ty; r < 32; r += 8)
    out[(size_t)(n0 + r) * K + k0 + tx] = (f16)tile[tx][r];
}

// ---------- omega (64 d x 128 m) f32 -> omT16 (128 m x 64 d) fp16 -----------------------------
__global__ __launch_bounds__(256) void omegaT_kernel(const float* __restrict__ om,
                                                     f16* __restrict__ omT) {
  int e = blockIdx.x * 256 + threadIdx.x;   // 8192 total
  int d = e >> 7, m = e & 127;
  omT[m * 64 + d] = (f16)om[e];
}

// ---------- init vT rows 64..79: row 64 = ones (den trick), 65..79 = zeros --------------------
__global__ __launch_bounds__(256) void vtinit_kernel(f16* __restrict__ vT) {
  int bh = blockIdx.x, dr = blockIdx.y;     // dr 0..15 -> d = 64+dr
  int t0 = threadIdx.x * 4;
  f16 val = (dr == 0) ? (f16)1.0f : (f16)0.0f;
  f16x4 o = {val, val, val, val};
  *(f16x4*)&vT[((size_t)bh * DEXT + 64 + dr) * 1024 + t0] = o;
}

// ---------- qkv GEMM (fp16 MFMA): writes qk16 [row][2048] and vT16 [bh][d][t] -----------------
__global__ __launch_bounds__(256) void gemm_qkv_kernel(
    const f16* __restrict__ A, const f16* __restrict__ B,
    const float* __restrict__ bias, f16* __restrict__ qk16, f16* __restrict__ vT16) {
  __shared__ f16 As[128 * 32];
  __shared__ f16 Bs[64 * 32];
  const int tid = threadIdx.x;
  const int wid = tid >> 6, lane = tid & 63;
  const int bm = blockIdx.y * 128, bn = blockIdx.x * 64;
  const int wr = (wid >> 1) * 64, wc = (wid & 1) * 32;
  const int sr = wid * 16 + (lane >> 2), sk = (lane & 3) * 8;
  const int frow = lane & 15, fk = (lane >> 4) * 8;
  f32x4 acc[4][2];
#pragma unroll
  for (int mi = 0; mi < 4; ++mi)
#pragma unroll
    for (int ni = 0; ni < 2; ++ni) acc[mi][ni] = f32x4{0.f, 0.f, 0.f, 0.f};
  for (int kt = 0; kt < 1024; kt += 32) {
    __syncthreads();
#pragma unroll
    for (int i = 0; i < 2; ++i)
      gload16(&A[(size_t)(bm + i * 64 + sr) * 1024 + kt + sk],
              (char*)As + i * 4096 + wid * 1024);
    gload16(&B[(size_t)(bn + sr) * 1024 + kt + sk], (char*)Bs + wid * 1024);
    __syncthreads();
    f16x8 af[4], bf[2];
#pragma unroll
    for (int mi = 0; mi < 4; ++mi)
      af[mi] = *(const f16x8*)&As[(wr + mi * 16 + frow) * 32 + fk];
#pragma unroll
    for (int ni = 0; ni < 2; ++ni)
      bf[ni] = *(const f16x8*)&Bs[(wc + ni * 16 + frow) * 32 + fk];
#pragma unroll
    for (int mi = 0; mi < 4; ++mi)
#pragma unroll
      for (int ni = 0; ni < 2; ++ni)
        acc[mi][ni] = __builtin_amdgcn_mfma_f32_16x16x32_f16(af[mi], bf[ni], acc[mi][ni], 0, 0, 0);
  }
#pragma unroll
  for (int ni = 0; ni < 2; ++ni) {
    int col = bn + wc + ni * 16 + frow;
    float bv = bias[col];
#pragma unroll
    for (int mi = 0; mi < 4; ++mi) {
      int row0 = bm + wr + mi * 16 + (lane >> 4) * 4;
#pragma unroll
      for (int r = 0; r < 4; ++r) {
        int row = row0 + r;
        f16 hv = (f16)(acc[mi][ni][r] + bv);
        if (col < 2048) {
          qk16[(size_t)row * 2048 + col] = hv;
        } else {
          int cc = col - 2048, hh = cc >> 6, d = cc & 63;
          int b = row >> 10, t = row & 1023;
          vT16[((size_t)(b * 16 + hh) * DEXT + d) * 1024 + t] = hv;
        }
      }
    }
  }
}

// ---------- plain fp16 GEMM -> f32 out + bias (for final proj) --------------------------------
__global__ __launch_bounds__(256) void gemm_out_kernel(
    const f16* __restrict__ A, const f16* __restrict__ B,
    const float* __restrict__ bias, float* __restrict__ C) {
  __shared__ f16 As[64 * 32];
  __shared__ f16 Bs[64 * 32];
  const int tid = threadIdx.x;
  const int wid = tid >> 6, lane = tid & 63;
  const int bm = blockIdx.y * 64, bn = blockIdx.x * 64;
  const int wr = (wid >> 1) * 32, wc = (wid & 1) * 32;
  const int sr = wid * 16 + (lane >> 2), sk = (lane & 3) * 8;
  const int frow = lane & 15, fk = (lane >> 4) * 8;
  f32x4 acc[2][2];
#pragma unroll
  for (int mi = 0; mi < 2; ++mi)
#pragma unroll
    for (int ni = 0; ni < 2; ++ni) acc[mi][ni] = f32x4{0.f, 0.f, 0.f, 0.f};
  for (int kt = 0; kt < 1024; kt += 32) {
    __syncthreads();
    gload16(&A[(size_t)(bm + sr) * 1024 + kt + sk], (char*)As + wid * 1024);
    gload16(&B[(size_t)(bn + sr) * 1024 + kt + sk], (char*)Bs + wid * 1024);
    __syncthreads();
    f16x8 af[2], bf[2];
#pragma unroll
    for (int mi = 0; mi < 2; ++mi)
      af[mi] = *(const f16x8*)&As[(wr + mi * 16 + frow) * 32 + fk];
#pragma unroll
    for (int ni = 0; ni < 2; ++ni)
      bf[ni] = *(const f16x8*)&Bs[(wc + ni * 16 + frow) * 32 + fk];
#pragma unroll
    for (int mi = 0; mi < 2; ++mi)
#pragma unroll
      for (int ni = 0; ni < 2; ++ni)
        acc[mi][ni] = __builtin_amdgcn_mfma_f32_16x16x32_f16(af[mi], bf[ni], acc[mi][ni], 0, 0, 0);
  }
#pragma unroll
  for (int ni = 0; ni < 2; ++ni) {
    int col = bn + wc + ni * 16 + frow;
    float bv = bias[col];
#pragma unroll
    for (int mi = 0; mi < 2; ++mi) {
      int row0 = bm + wr + mi * 16 + (lane >> 4) * 4;
#pragma unroll
      for (int r = 0; r < 4; ++r)
        C[(size_t)(row0 + r) * 1024 + col] = acc[mi][ni][r] + bv;
    }
  }
}

// ---------- phi (MFMA): per block (bh, 64-t tile, q|k) ----------------------------------------
// pass1: C[m][t] = omT @ q^T -> writes phi[t][m] vectorized
// pass2 (k only): C[t][m] = q @ omT^T -> writes phiT[m][t] vectorized
__global__ __launch_bounds__(256) void phi_kernel(const f16* __restrict__ qk16,
                                                  const f16* __restrict__ omT,
                                                  f16* __restrict__ phi_q,
                                                  f16* __restrict__ phi_k,
                                                  f16* __restrict__ phi_kT) {
  __shared__ f16 om_s[128 * 64];
  __shared__ f16 q_s[64 * 64];
  __shared__ float nsq_s[64];
  const int tid = threadIdx.x;
  const int wid = tid >> 6, lane = tid & 63;
  const int bh = blockIdx.x, tc = blockIdx.y, isK = blockIdx.z;
  const int b = bh >> 4, h = bh & 15;
  const int t0 = tc * 64;
  const int frow = lane & 15, fk = (lane >> 4) * 8;
  // stage omT (16 KB linear)
#pragma unroll
  for (int r = 0; r < 4; ++r)
    gload16(omT + r * 2048 + wid * 512 + lane * 8, (char*)om_s + r * 4096 + wid * 1024);
  // stage q/k tile 64x64
  {
    int rbase = b * 1024 + t0, cbase = isK * 1024 + h * 64;
#pragma unroll
    for (int r = 0; r < 2; ++r) {
      int row = r * 32 + wid * 8 + (lane >> 3);
      gload16(qk16 + (size_t)(rbase + row) * 2048 + cbase + (lane & 7) * 8,
              (char*)q_s + r * 4096 + wid * 1024);
    }
  }
  __syncthreads();
  if (tid < 64) {
    float s = 0.f;
#pragma unroll
    for (int j = 0; j < 8; ++j) {
      f16x8 v = *(const f16x8*)&q_s[tid * 64 + j * 8];
#pragma unroll
      for (int e = 0; e < 8; ++e) { float f = (float)v[e]; s += f * f; }
    }
    nsq_s[tid] = s;
  }
  // pass1 MFMA: A = omT rows m, B = q cols t
  f32x4 acc1[2][4];
#pragma unroll
  for (int mi = 0; mi < 2; ++mi)
#pragma unroll
    for (int ct = 0; ct < 4; ++ct) acc1[mi][ct] = f32x4{0.f, 0.f, 0.f, 0.f};
  {
    f16x8 af[2][2], bf[2];
#pragma unroll
    for (int mi = 0; mi < 2; ++mi)
#pragma unroll
      for (int kk = 0; kk < 2; ++kk)
        af[mi][kk] = *(const f16x8*)&om_s[(wid * 32 + mi * 16 + frow) * 64 + kk * 32 + fk];
#pragma unroll
    for (int ct = 0; ct < 4; ++ct) {
#pragma unroll
      for (int kk = 0; kk < 2; ++kk) {
        bf[kk] = *(const f16x8*)&q_s[(ct * 16 + frow) * 64 + kk * 32 + fk];
#pragma unroll
        for (int mi = 0; mi < 2; ++mi)
          acc1[mi][ct] = __builtin_amdgcn_mfma_f32_16x16x32_f16(af[mi][kk], bf[kk], acc1[mi][ct], 0, 0, 0);
      }
    }
  }
  // pass2 (k only): A = q rows t, B = omT cols m
  f32x4 acc2[8];
  if (isK) {
#pragma unroll
    for (int cm = 0; cm < 8; ++cm) acc2[cm] = f32x4{0.f, 0.f, 0.f, 0.f};
    f16x8 af2[2], bf2;
#pragma unroll
    for (int kk = 0; kk < 2; ++kk)
      af2[kk] = *(const f16x8*)&q_s[(wid * 16 + frow) * 64 + kk * 32 + fk];
#pragma unroll
    for (int cm = 0; cm < 8; ++cm)
#pragma unroll
      for (int kk = 0; kk < 2; ++kk) {
        bf2 = *(const f16x8*)&om_s[(cm * 16 + frow) * 64 + kk * 32 + fk];
        acc2[cm] = __builtin_amdgcn_mfma_f32_16x16x32_f16(af2[kk], bf2, acc2[cm], 0, 0, 0);
      }
  }
  __syncthreads();
  const float c2 = -0.5f * SCALE * SCALE;
  f16* dst = (isK ? phi_k : phi_q) + (size_t)bh * 1024 * 128 + (size_t)t0 * 128;
#pragma unroll
  for (int ct = 0; ct < 4; ++ct) {
    int t = ct * 16 + frow;
    float nh_ = c2 * nsq_s[t];
#pragma unroll
    for (int mi = 0; mi < 2; ++mi) {
      int m0 = wid * 32 + mi * 16 + (lane >> 4) * 4;
      f16x4 o;
#pragma unroll
      for (int r = 0; r < 4; ++r)
        o[r] = (f16)(__expf(SCALE * acc1[mi][ct][r] + nh_) * INV_SQRT_M);
      *(f16x4*)&dst[(size_t)t * 128 + m0] = o;
    }
  }
  if (isK) {
    int trow = wid * 16 + (lane >> 4) * 4;
    float4 n4 = *(float4*)&nsq_s[trow];
    float nn[4] = {c2 * n4.x, c2 * n4.y, c2 * n4.z, c2 * n4.w};
#pragma unroll
    for (int cm = 0; cm < 8; ++cm) {
      int m = cm * 16 + frow;
      f16x4 o;
#pragma unroll
      for (int r = 0; r < 4; ++r)
        o[r] = (f16)(__expf(SCALE * acc2[cm][r] + nn[r]) * INV_SQRT_M);
      *(f16x4*)&phi_kT[((size_t)bh * 128 + m) * 1024 + t0 + trow] = o;
    }
  }
}

// ---------- chunk sums (MFMA): ST[d'][m] = vT_ext @ phi_k, row 64 = Z -------------------------
__global__ __launch_bounds__(256) void chunk_sum_kernel(const f16* __restrict__ vT,
                                                        const f16* __restrict__ phi_kT,
                                                        f16* __restrict__ ST) {
  __shared__ f16 pkT_s[128 * 64];
  __shared__ f16 vt_s[DEXT * 64];
  const int tid = threadIdx.x;
  const int wid = tid >> 6, lane = tid & 63;
  const int bc = blockIdx.x;
  const int bh = bc / NC, c = bc % NC;
  const int tbase = c * LCH;
  const int frow = lane & 15, fk = (lane >> 4) * 8;
#pragma unroll
  for (int r = 0; r < 4; ++r) {
    int m = r * 32 + wid * 8 + (lane >> 3);
    gload16(phi_kT + ((size_t)bh * 128 + m) * 1024 + tbase + (lane & 7) * 8,
            (char*)pkT_s + r * 4096 + wid * 1024);
  }
  for (int rr = wid; rr < 10; rr += 4) {
    int d = rr * 8 + (lane >> 3);
    gload16(vT + ((size_t)bh * DEXT + d) * 1024 + tbase + (lane & 7) * 8,
            (char*)vt_s + rr * 1024);
  }
  __syncthreads();
  f32x4 acc[5][2];
#pragma unroll
  for (int dt = 0; dt < 5; ++dt)
#pragma unroll
    for (int cj = 0; cj < 2; ++cj) acc[dt][cj] = f32x4{0.f, 0.f, 0.f, 0.f};
  f16x8 af, bf[2][2];
#pragma unroll
  for (int cj = 0; cj < 2; ++cj)
#pragma unroll
    for (int kk = 0; kk < 2; ++kk)
      bf[cj][kk] = *(const f16x8*)&pkT_s[(wid * 32 + cj * 16 + frow) * 64 + kk * 32 + fk];
#pragma unroll
  for (int dt = 0; dt < 5; ++dt)
#pragma unroll
    for (int kk = 0; kk < 2; ++kk) {
      af = *(const f16x8*)&vt_s[(dt * 16 + frow) * 64 + kk * 32 + fk];
#pragma unroll
      for (int cj = 0; cj < 2; ++cj)
        acc[dt][cj] = __builtin_amdgcn_mfma_f32_16x16x32_f16(af, bf[cj][kk], acc[dt][cj], 0, 0, 0);
    }
  f16* dst = ST + (size_t)bc * (DEXT * 128);
#pragma unroll
  for (int dt = 0; dt < 5; ++dt)
#pragma unroll
    for (int cj = 0; cj < 2; ++cj) {
      int m = wid * 32 + cj * 16 + frow;
      int d0 = dt * 16 + (lane >> 4) * 4;
#pragma unroll
      for (int r = 0; r < 4; ++r)
        dst[(size_t)(d0 + r) * 128 + m] = (f16)acc[dt][cj][r];
    }
}

// ---------- exclusive prefix over chunks, in place (fp16, f32 accum) --------------------------
__global__ __launch_bounds__(256) void prefix_kernel(f16* __restrict__ ST) {
  int tid = threadIdx.x;
  int bh = blockIdx.x;
  int d = blockIdx.y * 16 + (tid >> 4), m0 = (tid & 15) * 8;
  float run[8] = {};
  for (int c = 0; c < NC; ++c) {
    f16* p = ST + ((size_t)(bh * NC + c) * DEXT + d) * 128 + m0;
    f16x8 v = *(f16x8*)p;
    f16x8 o;
#pragma unroll
    for (int j = 0; j < 8; ++j) {
      o[j] = (f16)run[j];
      run[j] += (float)v[j];
    }
    *(f16x8*)p = o;
  }
}

// ---------- intra (MFMA): QK^T -> causal A -> y = (A@Vext + phiq@SText) / den -----------------
__global__ __launch_bounds__(256) void intra_kernel(const f16* __restrict__ phi_q,
    const f16* __restrict__ phi_k, const f16* __restrict__ vT,
    const f16* __restrict__ ST, f16* __restrict__ y16) {
  __shared__ f16 pq_s[64 * 128];
  __shared__ f16 pk_s[64 * 128];
  __shared__ f16 st_s[DEXT * 128];
  __shared__ f16 vt_s[DEXT * 64];
  __shared__ f16 a_s[64 * 64];
  __shared__ float den_s[64];
  const int tid = threadIdx.x;
  const int wid = tid >> 6, lane = tid & 63;
  const int bc = blockIdx.x;
  const int bh = bc / NC, c = bc % NC;
  const int b = bh >> 4, h = bh & 15;
  const int tbase = c * LCH;
  const int frow = lane & 15, fk = (lane >> 4) * 8;
  // stage phi_q, phi_k (contiguous 16 KB each), ST (20 KB), vT tile (10 KB)
#pragma unroll
  for (int r = 0; r < 4; ++r) {
    size_t off = (size_t)r * 2048 + wid * 512 + lane * 8;
    gload16(phi_q + (size_t)bh * 131072 + (size_t)tbase * 128 + off,
            (char*)pq_s + r * 4096 + wid * 1024);
    gload16(phi_k + (size_t)bh * 131072 + (size_t)tbase * 128 + off,
            (char*)pk_s + r * 4096 + wid * 1024);
  }
#pragma unroll
  for (int r = 0; r < 5; ++r)
    gload16(ST + (size_t)bc * (DEXT * 128) + r * 2048 + wid * 512 + lane * 8,
            (char*)st_s + r * 4096 + wid * 1024);
  for (int rr = wid; rr < 10; rr += 4) {
    int d = rr * 8 + (lane >> 3);
    gload16(vT + ((size_t)bh * DEXT + d) * 1024 + tbase + (lane & 7) * 8,
            (char*)vt_s + rr * 1024);
  }
  __syncthreads();
  // QK^T swapped: A = phi_k rows tk (wave-owned), B = phi_q cols tq -> C'[tk][tq]
  {
    f32x4 accq[4];
#pragma unroll
    for (int ct = 0; ct < 4; ++ct) accq[ct] = f32x4{0.f, 0.f, 0.f, 0.f};
    f16x8 af[4], bf;
#pragma unroll
    for (int kk = 0; kk < 4; ++kk)
      af[kk] = *(const f16x8*)&pk_s[(wid * 16 + frow) * 128 + kk * 32 + fk];
#pragma unroll
    for (int ct = 0; ct < 4; ++ct)
#pragma unroll
      for (int kk = 0; kk < 4; ++kk) {
        bf = *(const f16x8*)&pq_s[(ct * 16 + frow) * 128 + kk * 32 + fk];
        accq[ct] = __builtin_amdgcn_mfma_f32_16x16x32_f16(af[kk], bf, accq[ct], 0, 0, 0);
      }
    // causal mask + write A[tq][tk] (vectorized over tk)
    int tkbase = wid * 16 + (lane >> 4) * 4;
#pragma unroll
    for (int ct = 0; ct < 4; ++ct) {
      int tq = ct * 16 + frow;
      f16x4 av;
#pragma unroll
      for (int r = 0; r < 4; ++r)
        av[r] = (f16)((tkbase + r <= tq) ? accq[ct][r] : 0.f);
      *(f16x4*)&a_s[tq * 64 + tkbase] = av;
    }
  }
  __syncthreads();
  // phase 2: y_ext[ti][d'] = A @ vT_ext + phi_q @ ST_ext  (col 64 = den)
  f32x4 acc2[5];
#pragma unroll
  for (int ct = 0; ct < 5; ++ct) acc2[ct] = f32x4{0.f, 0.f, 0.f, 0.f};
  {
    f16x8 afA[2], afP[4], bfv;
#pragma unroll
    for (int kk = 0; kk < 2; ++kk)
      afA[kk] = *(const f16x8*)&a_s[(wid * 16 + frow) * 64 + kk * 32 + fk];
#pragma unroll
    for (int kk = 0; kk < 4; ++kk)
      afP[kk] = *(const f16x8*)&pq_s[(wid * 16 + frow) * 128 + kk * 32 + fk];
#pragma unroll
    for (int ct = 0; ct < 5; ++ct) {
#pragma unroll
      for (int kk = 0; kk < 2; ++kk) {
        bfv = *(const f16x8*)&vt_s[(ct * 16 + frow) * 64 + kk * 32 + fk];
        acc2[ct] = __builtin_amdgcn_mfma_f32_16x16x32_f16(afA[kk], bfv, acc2[ct], 0, 0, 0);
      }
#pragma unroll
      for (int kk = 0; kk < 4; ++kk) {
        bfv = *(const f16x8*)&st_s[(ct * 16 + frow) * 128 + kk * 32 + fk];
        acc2[ct] = __builtin_amdgcn_mfma_f32_16x16x32_f16(afP[kk], bfv, acc2[ct], 0, 0, 0);
      }
    }
  }
  // den from col 64 (ct=4, frow==0 lanes)
  if (frow == 0) {
    int t0g = wid * 16 + (lane >> 4) * 4;
#pragma unroll
    for (int r = 0; r < 4; ++r) den_s[t0g + r] = acc2[4][r];
  }
  __syncthreads();
  {
    int t0g = wid * 16 + (lane >> 4) * 4;
    float4 d4 = *(float4*)&den_s[t0g];
    float inv[4] = {1.f / (d4.x + EPSV), 1.f / (d4.y + EPSV),
                    1.f / (d4.z + EPSV), 1.f / (d4.w + EPSV)};
#pragma unroll
    for (int ct = 0; ct < 4; ++ct) {
      int d = ct * 16 + frow;
#pragma unroll
      for (int r = 0; r < 4; ++r) {
        int t = t0g + r;
        y16[(size_t)(b * 1024 + tbase + t) * 1024 + h * 64 + d] =
            (f16)(acc2[ct][r] * inv[r]);
      }
    }
  }
}

extern "C" void kernel_launch(void* const* d_in, const int* in_sizes, int n_in,
                              void* d_out, int out_size, void* d_ws, size_t ws_size,
                              hipStream_t stream) {
  const float* x      = (const float*)d_in[0];
  const float* W_attn = (const float*)d_in[1];
  const float* b_attn = (const float*)d_in[2];
  const float* W_proj = (const float*)d_in[3];
  const float* b_proj = (const float*)d_in[4];
  const float* omega  = (const float*)d_in[5];
  float* out = (float*)d_out;

  char* base = (char*)d_ws;
  f16* x16    = (f16*)(base);                     // 4,194,304 B
  f16* B16    = (f16*)(base + 4194304);           // 6,291,456 B (W^T fp16)
  f16* qk16   = (f16*)(base + 10485760);          // 8,388,608 B  [y16 aliases]
  f16* vT16   = (f16*)(base + 18874368);          // 5,242,880 B  [80 x 1024 per bh]
  f16* phi_q  = (f16*)(base + 24117248);          // 8,388,608 B
  f16* phi_k  = (f16*)(base + 32505856);          // 8,388,608 B
  f16* phi_kT = (f16*)(base + 40894464);          // 8,388,608 B
  f16* ST     = (f16*)(base + 49283072);          // 10,485,760 B [512 x 80 x 128]
  f16* omT16  = (f16*)(base + 59768832);          // 16,384 B
  f16* y16    = qk16;                             // alias: qk16 dead after phi

  conv16_kernel<<<2048, 256, 0, stream>>>(x, x16);
  tr16_kernel<<<dim3(96, 32), 256, 0, stream>>>(W_attn, B16, 1024, 3072);
  omegaT_kernel<<<32, 256, 0, stream>>>(omega, omT16);
  vtinit_kernel<<<dim3(32, 16), 256, 0, stream>>>(vT16);
  gemm_qkv_kernel<<<dim3(48, 16), 256, 0, stream>>>(x16, B16, b_attn, qk16, vT16);
  tr16_kernel<<<dim3(32, 32), 256, 0, stream>>>(W_proj, B16, 1024, 1024);
  phi_kernel<<<dim3(32, 16, 2), 256, 0, stream>>>(qk16, omT16, phi_q, phi_k, phi_kT);
  chunk_sum_kernel<<<512, 256, 0, stream>>>(vT16, phi_kT, ST);
  prefix_kernel<<<dim3(32, 5), 256, 0, stream>>>(ST);
  intra_kernel<<<512, 256, 0, stream>>>(phi_q, phi_k, vT16, ST, y16);
  gemm_out_kernel<<<dim3(16, 32), 256, 0, stream>>>(y16, B16, b_proj, out);
}

// Round 5
// 88.436 us; speedup vs baseline: 4.4752x; 1.1268x over previous
//
#include <hip/hip_runtime.h>
#include <math.h>

#define B_ 2
#define T_ 1024
#define C_ 1024
#define NH 16
#define DH 64
#define M_ 128
#define LCH 64
#define NC (T_/LCH)          // 16 chunks
#define DEXT 80              // 64 d + den-row(64) + pad

constexpr float SCALE = 0.125f;              // 1/sqrt(64)
constexpr float EPSV = 1e-6f;
constexpr float INV_SQRT_M = 0.088388347648318447f;  // 1/sqrt(128)

typedef _Float16 f16;
typedef f16 f16x4 __attribute__((ext_vector_type(4)));
typedef f16 f16x8 __attribute__((ext_vector_type(8)));
typedef float f32x4 __attribute__((ext_vector_type(4)));

typedef const __attribute__((address_space(1))) void* as1_cvoid_p;
typedef __attribute__((address_space(3))) void* as3_void_p;

__device__ __forceinline__ void gload16(const void* g, void* l) {
  __builtin_amdgcn_global_load_lds((as1_cvoid_p)g, (as3_void_p)l, 16, 0, 0);
}

// swizzled element index: row of (slots*8) f16, 16B-slot XOR'd by low row bits
__device__ __forceinline__ int sw4(int row, int slot)  { return row * 32  + ((slot ^ (row & 3))  << 3); }
__device__ __forceinline__ int sw8(int row, int slot)  { return row * 64  + ((slot ^ (row & 7))  << 3); }
__device__ __forceinline__ int sw16(int row, int slot) { return row * 128 + ((slot ^ (row & 15)) << 3); }

// ---------- prep: x->fp16, omega transpose, vT den-rows init ----------------------------------
__global__ __launch_bounds__(256) void prep_kernel(const float* __restrict__ x,
                                                   const float* __restrict__ omega,
                                                   f16* __restrict__ x16,
                                                   f16* __restrict__ omT,
                                                   f16* __restrict__ vT) {
  int bid = blockIdx.x, tid = threadIdx.x;
  if (bid < 2048) {
    int i = (bid * 256 + tid) * 4;
    float4 v = *(const float4*)&x[i];
    f16x4 o = {(f16)v.x, (f16)v.y, (f16)v.z, (f16)v.w};
    *(f16x4*)&x16[i] = o;
  } else if (bid < 2080) {
    int e = (bid - 2048) * 256 + tid;
    int d = e >> 7, m = e & 127;
    omT[m * 64 + d] = (f16)omega[e];
  } else {
    int idx = bid - 2080;             // 0..511
    int bh = idx >> 4, dr = idx & 15;
    f16 val = (dr == 0) ? (f16)1.0f : (f16)0.0f;
    f16x4 o = {val, val, val, val};
    *(f16x4*)&vT[((size_t)bh * DEXT + 64 + dr) * 1024 + tid * 4] = o;
  }
}

// ---------- both weight transposes: fp32 (K x N) -> fp16 [n][K] -------------------------------
__global__ __launch_bounds__(256) void tr_both_kernel(const float* __restrict__ Wa,
                                                      const float* __restrict__ Wp,
                                                      f16* __restrict__ B16,
                                                      f16* __restrict__ B16p) {
  __shared__ float tile[32][33];
  int bid = blockIdx.x, tid = threadIdx.x;
  const float* in; f16* out; int N, n0, k0;
  if (bid < 3072) { in = Wa; out = B16;  N = 3072; n0 = (bid % 96) * 32; k0 = (bid / 96) * 32; }
  else { int b2 = bid - 3072; in = Wp; out = B16p; N = 1024; n0 = (b2 & 31) * 32; k0 = (b2 >> 5) * 32; }
  int tx = tid & 31, ty = tid >> 5;
  for (int r = ty; r < 32; r += 8)
    tile[r][tx] = in[(size_t)(k0 + r) * N + n0 + tx];
  __syncthreads();
  for (int r = ty; r < 32; r += 8)
    out[(size_t)(n0 + r) * 1024 + k0 + tx] = (f16)tile[tx][r];
}

// ---------- qkv GEMM (fp16 MFMA, dbuf prefetch): qk16 [row][2048], vT16 [bh][d][t] ------------
__global__ __launch_bounds__(256) void gemm_qkv_kernel(
    const f16* __restrict__ A, const f16* __restrict__ B,
    const float* __restrict__ bias, f16* __restrict__ qk16, f16* __restrict__ vT16) {
  __shared__ f16 As[2][128 * 32];
  __shared__ f16 Bs[2][64 * 32];
  const int tid = threadIdx.x;
  const int wid = tid >> 6, lane = tid & 63;
  const int bm = blockIdx.y * 128, bn = blockIdx.x * 64;
  const int wr = (wid >> 1) * 64, wc = (wid & 1) * 32;
  const int sr = wid * 16 + (lane >> 2);
  const int sk = ((lane & 3) ^ (sr & 3)) * 8;      // pre-swizzled source chunk
  const int frow = lane & 15, fkc = lane >> 4;
  f32x4 acc[4][2];
#pragma unroll
  for (int mi = 0; mi < 4; ++mi)
#pragma unroll
    for (int ni = 0; ni < 2; ++ni) acc[mi][ni] = f32x4{0.f, 0.f, 0.f, 0.f};

  auto STAGE = [&](int buf, int kt) {
#pragma unroll
    for (int i = 0; i < 2; ++i)
      gload16(&A[(size_t)(bm + i * 64 + sr) * 1024 + kt + sk],
              (char*)As[buf] + i * 4096 + wid * 1024);
    gload16(&B[(size_t)(bn + sr) * 1024 + kt + sk], (char*)Bs[buf] + wid * 1024);
  };
  STAGE(0, 0);
  for (int kt = 0; kt < 1024; kt += 32) {
    const int cur = (kt >> 5) & 1;
    if (kt + 32 < 1024) {
      STAGE(cur ^ 1, kt + 32);
      asm volatile("s_waitcnt vmcnt(3)" ::: "memory");
    } else {
      asm volatile("s_waitcnt vmcnt(0)" ::: "memory");
    }
    __builtin_amdgcn_s_barrier();
    asm volatile("" ::: "memory");
    f16x8 af[4], bf[2];
#pragma unroll
    for (int mi = 0; mi < 4; ++mi)
      af[mi] = *(const f16x8*)&As[cur][sw4(wr + mi * 16 + frow, fkc)];
#pragma unroll
    for (int ni = 0; ni < 2; ++ni)
      bf[ni] = *(const f16x8*)&Bs[cur][sw4(wc + ni * 16 + frow, fkc)];
#pragma unroll
    for (int mi = 0; mi < 4; ++mi)
#pragma unroll
      for (int ni = 0; ni < 2; ++ni)
        acc[mi][ni] = __builtin_amdgcn_mfma_f32_16x16x32_f16(af[mi], bf[ni], acc[mi][ni], 0, 0, 0);
    asm volatile("" ::: "memory");
    __builtin_amdgcn_s_barrier();
  }
#pragma unroll
  for (int ni = 0; ni < 2; ++ni) {
    int col = bn + wc + ni * 16 + frow;
    float bv = bias[col];
#pragma unroll
    for (int mi = 0; mi < 4; ++mi) {
      int row0 = bm + wr + mi * 16 + (lane >> 4) * 4;
#pragma unroll
      for (int r = 0; r < 4; ++r) {
        int row = row0 + r;
        f16 hv = (f16)(acc[mi][ni][r] + bv);
        if (col < 2048) {
          qk16[(size_t)row * 2048 + col] = hv;
        } else {
          int cc = col - 2048, hh = cc >> 6, d = cc & 63;
          int b = row >> 10, t = row & 1023;
          vT16[((size_t)(b * 16 + hh) * DEXT + d) * 1024 + t] = hv;
        }
      }
    }
  }
}

// ---------- final proj GEMM (fp16 MFMA, dbuf prefetch) -> f32 out -----------------------------
__global__ __launch_bounds__(256) void gemm_out_kernel(
    const f16* __restrict__ A, const f16* __restrict__ B,
    const float* __restrict__ bias, float* __restrict__ C) {
  __shared__ f16 As[2][64 * 32];
  __shared__ f16 Bs[2][64 * 32];
  const int tid = threadIdx.x;
  const int wid = tid >> 6, lane = tid & 63;
  const int bm = blockIdx.y * 64, bn = blockIdx.x * 64;
  const int wr = (wid >> 1) * 32, wc = (wid & 1) * 32;
  const int sr = wid * 16 + (lane >> 2);
  const int sk = ((lane & 3) ^ (sr & 3)) * 8;
  const int frow = lane & 15, fkc = lane >> 4;
  f32x4 acc[2][2];
#pragma unroll
  for (int mi = 0; mi < 2; ++mi)
#pragma unroll
    for (int ni = 0; ni < 2; ++ni) acc[mi][ni] = f32x4{0.f, 0.f, 0.f, 0.f};

  auto STAGE = [&](int buf, int kt) {
    gload16(&A[(size_t)(bm + sr) * 1024 + kt + sk], (char*)As[buf] + wid * 1024);
    gload16(&B[(size_t)(bn + sr) * 1024 + kt + sk], (char*)Bs[buf] + wid * 1024);
  };
  STAGE(0, 0);
  for (int kt = 0; kt < 1024; kt += 32) {
    const int cur = (kt >> 5) & 1;
    if (kt + 32 < 1024) {
      STAGE(cur ^ 1, kt + 32);
      asm volatile("s_waitcnt vmcnt(2)" ::: "memory");
    } else {
      asm volatile("s_waitcnt vmcnt(0)" ::: "memory");
    }
    __builtin_amdgcn_s_barrier();
    asm volatile("" ::: "memory");
    f16x8 af[2], bf[2];
#pragma unroll
    for (int mi = 0; mi < 2; ++mi)
      af[mi] = *(const f16x8*)&As[cur][sw4(wr + mi * 16 + frow, fkc)];
#pragma unroll
    for (int ni = 0; ni < 2; ++ni)
      bf[ni] = *(const f16x8*)&Bs[cur][sw4(wc + ni * 16 + frow, fkc)];
#pragma unroll
    for (int mi = 0; mi < 2; ++mi)
#pragma unroll
      for (int ni = 0; ni < 2; ++ni)
        acc[mi][ni] = __builtin_amdgcn_mfma_f32_16x16x32_f16(af[mi], bf[ni], acc[mi][ni], 0, 0, 0);
    asm volatile("" ::: "memory");
    __builtin_amdgcn_s_barrier();
  }
#pragma unroll
  for (int ni = 0; ni < 2; ++ni) {
    int col = bn + wc + ni * 16 + frow;
    float bv = bias[col];
#pragma unroll
    for (int mi = 0; mi < 2; ++mi) {
      int row0 = bm + wr + mi * 16 + (lane >> 4) * 4;
#pragma unroll
      for (int r = 0; r < 4; ++r)
        C[(size_t)(row0 + r) * 1024 + col] = acc[mi][ni][r] + bv;
    }
  }
}

// ---------- phi (MFMA): per block (bh, 64-t tile, q|k); swizzled LDS --------------------------
__global__ __launch_bounds__(256) void phi_kernel(const f16* __restrict__ qk16,
                                                  const f16* __restrict__ omT,
                                                  f16* __restrict__ phi_q,
                                                  f16* __restrict__ phi_k,
                                                  f16* __restrict__ phi_kT) {
  __shared__ f16 om_s[128 * 64];
  __shared__ f16 q_s[64 * 64];
  __shared__ float nsq_s[64];
  const int tid = threadIdx.x;
  const int wid = tid >> 6, lane = tid & 63;
  const int bh = blockIdx.x, tc = blockIdx.y, isK = blockIdx.z;
  const int b = bh >> 4, h = bh & 15;
  const int t0 = tc * 64;
  const int frow = lane & 15, fkc = lane >> 4;
#pragma unroll
  for (int r = 0; r < 4; ++r) {
    int row = r * 32 + wid * 8 + (lane >> 3);
    gload16(omT + row * 64 + ((lane & 7) ^ (row & 7)) * 8,
            (char*)om_s + r * 4096 + wid * 1024);
  }
  {
    int rbase = b * 1024 + t0, cbase = isK * 1024 + h * 64;
#pragma unroll
    for (int r = 0; r < 2; ++r) {
      int row = r * 32 + wid * 8 + (lane >> 3);
      gload16(qk16 + (size_t)(rbase + row) * 2048 + cbase + ((lane & 7) ^ (row & 7)) * 8,
              (char*)q_s + r * 4096 + wid * 1024);
    }
  }
  __syncthreads();
  if (tid < 64) {
    float s = 0.f;
#pragma unroll
    for (int j = 0; j < 8; ++j) {
      f16x8 v = *(const f16x8*)&q_s[sw8(tid, j)];
#pragma unroll
      for (int e = 0; e < 8; ++e) { float f = (float)v[e]; s += f * f; }
    }
    nsq_s[tid] = s;
  }
  // pass1: C[m][t] = omT @ q^T
  f32x4 acc1[2][4];
#pragma unroll
  for (int mi = 0; mi < 2; ++mi)
#pragma unroll
    for (int ct = 0; ct < 4; ++ct) acc1[mi][ct] = f32x4{0.f, 0.f, 0.f, 0.f};
  {
    f16x8 af[2][2], bf[2];
#pragma unroll
    for (int mi = 0; mi < 2; ++mi)
#pragma unroll
      for (int kk = 0; kk < 2; ++kk)
        af[mi][kk] = *(const f16x8*)&om_s[sw8(wid * 32 + mi * 16 + frow, kk * 4 + fkc)];
#pragma unroll
    for (int ct = 0; ct < 4; ++ct) {
#pragma unroll
      for (int kk = 0; kk < 2; ++kk) {
        bf[kk] = *(const f16x8*)&q_s[sw8(ct * 16 + frow, kk * 4 + fkc)];
#pragma unroll
        for (int mi = 0; mi < 2; ++mi)
          acc1[mi][ct] = __builtin_amdgcn_mfma_f32_16x16x32_f16(af[mi][kk], bf[kk], acc1[mi][ct], 0, 0, 0);
      }
    }
  }
  // pass2 (k only): C[t][m] = q @ omT^T
  f32x4 acc2[8];
  if (isK) {
#pragma unroll
    for (int cm = 0; cm < 8; ++cm) acc2[cm] = f32x4{0.f, 0.f, 0.f, 0.f};
    f16x8 af2[2], bf2;
#pragma unroll
    for (int kk = 0; kk < 2; ++kk)
      af2[kk] = *(const f16x8*)&q_s[sw8(wid * 16 + frow, kk * 4 + fkc)];
#pragma unroll
    for (int cm = 0; cm < 8; ++cm)
#pragma unroll
      for (int kk = 0; kk < 2; ++kk) {
        bf2 = *(const f16x8*)&om_s[sw8(cm * 16 + frow, kk * 4 + fkc)];
        acc2[cm] = __builtin_amdgcn_mfma_f32_16x16x32_f16(af2[kk], bf2, acc2[cm], 0, 0, 0);
      }
  }
  __syncthreads();
  const float c2 = -0.5f * SCALE * SCALE;
  f16* dst = (isK ? phi_k : phi_q) + (size_t)bh * 1024 * 128 + (size_t)t0 * 128;
#pragma unroll
  for (int ct = 0; ct < 4; ++ct) {
    int t = ct * 16 + frow;
    float nh_ = c2 * nsq_s[t];
#pragma unroll
    for (int mi = 0; mi < 2; ++mi) {
      int m0 = wid * 32 + mi * 16 + (lane >> 4) * 4;
      f16x4 o;
#pragma unroll
      for (int r = 0; r < 4; ++r)
        o[r] = (f16)(__expf(SCALE * acc1[mi][ct][r] + nh_) * INV_SQRT_M);
      *(f16x4*)&dst[(size_t)t * 128 + m0] = o;
    }
  }
  if (isK) {
    int trow = wid * 16 + (lane >> 4) * 4;
    float4 n4 = *(float4*)&nsq_s[trow];
    float nn[4] = {c2 * n4.x, c2 * n4.y, c2 * n4.z, c2 * n4.w};
#pragma unroll
    for (int cm = 0; cm < 8; ++cm) {
      int m = cm * 16 + frow;
      f16x4 o;
#pragma unroll
      for (int r = 0; r < 4; ++r)
        o[r] = (f16)(__expf(SCALE * acc2[cm][r] + nn[r]) * INV_SQRT_M);
      *(f16x4*)&phi_kT[((size_t)bh * 128 + m) * 1024 + t0 + trow] = o;
    }
  }
}

// ---------- chunk sums (MFMA): ST[d'][m] = vT_ext @ phi_k, row 64 = Z -------------------------
__global__ __launch_bounds__(256) void chunk_sum_kernel(const f16* __restrict__ vT,
                                                        const f16* __restrict__ phi_kT,
                                                        f16* __restrict__ ST) {
  __shared__ f16 pkT_s[128 * 64];
  __shared__ f16 vt_s[DEXT * 64];
  const int tid = threadIdx.x;
  const int wid = tid >> 6, lane = tid & 63;
  const int bc = blockIdx.x;
  const int bh = bc / NC, c = bc % NC;
  const int tbase = c * LCH;
  const int frow = lane & 15, fkc = lane >> 4;
#pragma unroll
  for (int r = 0; r < 4; ++r) {
    int m = r * 32 + wid * 8 + (lane >> 3);
    gload16(phi_kT + ((size_t)bh * 128 + m) * 1024 + tbase + ((lane & 7) ^ (m & 7)) * 8,
            (char*)pkT_s + r * 4096 + wid * 1024);
  }
  for (int rr = wid; rr < 10; rr += 4) {
    int d = rr * 8 + (lane >> 3);
    gload16(vT + ((size_t)bh * DEXT + d) * 1024 + tbase + ((lane & 7) ^ (d & 7)) * 8,
            (char*)vt_s + rr * 1024);
  }
  __syncthreads();
  f32x4 acc[5][2];
#pragma unroll
  for (int dt = 0; dt < 5; ++dt)
#pragma unroll
    for (int cj = 0; cj < 2; ++cj) acc[dt][cj] = f32x4{0.f, 0.f, 0.f, 0.f};
  f16x8 af, bf[2][2];
#pragma unroll
  for (int cj = 0; cj < 2; ++cj)
#pragma unroll
    for (int kk = 0; kk < 2; ++kk)
      bf[cj][kk] = *(const f16x8*)&pkT_s[sw8(wid * 32 + cj * 16 + frow, kk * 4 + fkc)];
#pragma unroll
  for (int dt = 0; dt < 5; ++dt)
#pragma unroll
    for (int kk = 0; kk < 2; ++kk) {
      af = *(const f16x8*)&vt_s[sw8(dt * 16 + frow, kk * 4 + fkc)];
#pragma unroll
      for (int cj = 0; cj < 2; ++cj)
        acc[dt][cj] = __builtin_amdgcn_mfma_f32_16x16x32_f16(af, bf[cj][kk], acc[dt][cj], 0, 0, 0);
    }
  f16* dst = ST + (size_t)bc * (DEXT * 128);
#pragma unroll
  for (int dt = 0; dt < 5; ++dt)
#pragma unroll
    for (int cj = 0; cj < 2; ++cj) {
      int m = wid * 32 + cj * 16 + frow;
      int d0 = dt * 16 + (lane >> 4) * 4;
#pragma unroll
      for (int r = 0; r < 4; ++r)
        dst[(size_t)(d0 + r) * 128 + m] = (f16)acc[dt][cj][r];
    }
}

// ---------- exclusive prefix over chunks, in place (fp16, f32 accum) --------------------------
__global__ __launch_bounds__(256) void prefix_kernel(f16* __restrict__ ST) {
  int tid = threadIdx.x;
  int bh = blockIdx.x;
  int d = blockIdx.y * 16 + (tid >> 4), m0 = (tid & 15) * 8;
  float run[8] = {};
  for (int c = 0; c < NC; ++c) {
    f16* p = ST + ((size_t)(bh * NC + c) * DEXT + d) * 128 + m0;
    f16x8 v = *(f16x8*)p;
    f16x8 o;
#pragma unroll
    for (int j = 0; j < 8; ++j) {
      o[j] = (f16)run[j];
      run[j] += (float)v[j];
    }
    *(f16x8*)p = o;
  }
}

// ---------- intra (MFMA): QK^T -> causal A -> y = (A@Vext + phiq@SText) / den -----------------
__global__ __launch_bounds__(256) void intra_kernel(const f16* __restrict__ phi_q,
    const f16* __restrict__ phi_k, const f16* __restrict__ vT,
    const f16* __restrict__ ST, f16* __restrict__ y16) {
  __shared__ f16 pq_s[64 * 128];
  __shared__ f16 pk_s[64 * 128];
  __shared__ f16 st_s[DEXT * 128];
  __shared__ f16 vt_s[DEXT * 64];
  __shared__ f16 a_s[64 * 64];
  __shared__ float den_s[64];
  const int tid = threadIdx.x;
  const int wid = tid >> 6, lane = tid & 63;
  const int bc = blockIdx.x;
  const int bh = bc / NC, c = bc % NC;
  const int b = bh >> 4, h = bh & 15;
  const int tbase = c * LCH;
  const int frow = lane & 15, fkc = lane >> 4;
  // stage phi_q, phi_k (swizzled [t][128]), ST (swizzled [d'][128]), vT tile (swizzled [d][64])
#pragma unroll
  for (int r = 0; r < 4; ++r) {
    int row = r * 16 + wid * 4 + (lane >> 4);
    int col = ((lane & 15) ^ (row & 15)) * 8;
    gload16(phi_q + (size_t)bh * 131072 + (size_t)(tbase + row) * 128 + col,
            (char*)pq_s + r * 4096 + wid * 1024);
    gload16(phi_k + (size_t)bh * 131072 + (size_t)(tbase + row) * 128 + col,
            (char*)pk_s + r * 4096 + wid * 1024);
  }
#pragma unroll
  for (int r = 0; r < 5; ++r) {
    int row = r * 16 + wid * 4 + (lane >> 4);
    int col = ((lane & 15) ^ (row & 15)) * 8;
    gload16(ST + (size_t)bc * (DEXT * 128) + (size_t)row * 128 + col,
            (char*)st_s + r * 4096 + wid * 1024);
  }
  for (int rr = wid; rr < 10; rr += 4) {
    int d = rr * 8 + (lane >> 3);
    gload16(vT + ((size_t)bh * DEXT + d) * 1024 + tbase + ((lane & 7) ^ (d & 7)) * 8,
            (char*)vt_s + rr * 1024);
  }
  __syncthreads();
  // QK^T swapped: A = phi_k rows tk (wave-owned), B = phi_q cols tq -> C'[tk][tq]
  {
    f32x4 accq[4];
#pragma unroll
    for (int ct = 0; ct < 4; ++ct) accq[ct] = f32x4{0.f, 0.f, 0.f, 0.f};
    f16x8 af[4], bf;
#pragma unroll
    for (int kk = 0; kk < 4; ++kk)
      af[kk] = *(const f16x8*)&pk_s[sw16(wid * 16 + frow, kk * 4 + fkc)];
#pragma unroll
    for (int ct = 0; ct < 4; ++ct)
#pragma unroll
      for (int kk = 0; kk < 4; ++kk) {
        bf = *(const f16x8*)&pq_s[sw16(ct * 16 + frow, kk * 4 + fkc)];
        accq[ct] = __builtin_amdgcn_mfma_f32_16x16x32_f16(af[kk], bf, accq[ct], 0, 0, 0);
      }
    // causal mask + write A[tq][tk] swizzled (8B sub-slot preserved)
    int tkbase = wid * 16 + fkc * 4;
    int slot = tkbase >> 3, sub = tkbase & 4;
#pragma unroll
    for (int ct = 0; ct < 4; ++ct) {
      int tq = ct * 16 + frow;
      f16x4 av;
#pragma unroll
      for (int r = 0; r < 4; ++r)
        av[r] = (f16)((tkbase + r <= tq) ? accq[ct][r] : 0.f);
      *(f16x4*)&a_s[tq * 64 + ((slot ^ (tq & 7)) << 3) + sub] = av;
    }
  }
  __syncthreads();
  // phase 2: y_ext[ti][d'] = A @ vT_ext + phi_q @ ST_ext  (col 64 = den)
  f32x4 acc2[5];
#pragma unroll
  for (int ct = 0; ct < 5; ++ct) acc2[ct] = f32x4{0.f, 0.f, 0.f, 0.f};
  {
    f16x8 afA[2], afP[4], bfv;
#pragma unroll
    for (int kk = 0; kk < 2; ++kk)
      afA[kk] = *(const f16x8*)&a_s[sw8(wid * 16 + frow, kk * 4 + fkc)];
#pragma unroll
    for (int kk = 0; kk < 4; ++kk)
      afP[kk] = *(const f16x8*)&pq_s[sw16(wid * 16 + frow, kk * 4 + fkc)];
#pragma unroll
    for (int ct = 0; ct < 5; ++ct) {
#pragma unroll
      for (int kk = 0; kk < 2; ++kk) {
        bfv = *(const f16x8*)&vt_s[sw8(ct * 16 + frow, kk * 4 + fkc)];
        acc2[ct] = __builtin_amdgcn_mfma_f32_16x16x32_f16(afA[kk], bfv, acc2[ct], 0, 0, 0);
      }
#pragma unroll
      for (int kk = 0; kk < 4; ++kk) {
        bfv = *(const f16x8*)&st_s[sw16(ct * 16 + frow, kk * 4 + fkc)];
        acc2[ct] = __builtin_amdgcn_mfma_f32_16x16x32_f16(afP[kk], bfv, acc2[ct], 0, 0, 0);
      }
    }
  }
  if (frow == 0) {
    int t0g = wid * 16 + (lane >> 4) * 4;
#pragma unroll
    for (int r = 0; r < 4; ++r) den_s[t0g + r] = acc2[4][r];
  }
  __syncthreads();
  {
    int t0g = wid * 16 + (lane >> 4) * 4;
    float4 d4 = *(float4*)&den_s[t0g];
    float inv[4] = {1.f / (d4.x + EPSV), 1.f / (d4.y + EPSV),
                    1.f / (d4.z + EPSV), 1.f / (d4.w + EPSV)};
#pragma unroll
    for (int ct = 0; ct < 4; ++ct) {
      int d = ct * 16 + frow;
#pragma unroll
      for (int r = 0; r < 4; ++r) {
        int t = t0g + r;
        y16[(size_t)(b * 1024 + tbase + t) * 1024 + h * 64 + d] =
            (f16)(acc2[ct][r] * inv[r]);
      }
    }
  }
}

extern "C" void kernel_launch(void* const* d_in, const int* in_sizes, int n_in,
                              void* d_out, int out_size, void* d_ws, size_t ws_size,
                              hipStream_t stream) {
  const float* x      = (const float*)d_in[0];
  const float* W_attn = (const float*)d_in[1];
  const float* b_attn = (const float*)d_in[2];
  const float* W_proj = (const float*)d_in[3];
  const float* b_proj = (const float*)d_in[4];
  const float* omega  = (const float*)d_in[5];
  float* out = (float*)d_out;

  char* base = (char*)d_ws;
  f16* x16    = (f16*)(base);                     // 4,194,304 B
  f16* B16    = (f16*)(base + 4194304);           // 6,291,456 B (W_attn^T fp16)
  f16* qk16   = (f16*)(base + 10485760);          // 8,388,608 B  [y16 aliases]
  f16* vT16   = (f16*)(base + 18874368);          // 5,242,880 B  [80 x 1024 per bh]
  f16* phi_q  = (f16*)(base + 24117248);          // 8,388,608 B
  f16* phi_k  = (f16*)(base + 32505856);          // 8,388,608 B
  f16* phi_kT = (f16*)(base + 40894464);          // 8,388,608 B
  f16* ST     = (f16*)(base + 49283072);          // 10,485,760 B [512 x 80 x 128]
  f16* omT16  = (f16*)(base + 59768832);          // 16,384 B
  f16* B16p   = (f16*)(base + 59785216);          // 2,097,152 B (W_proj^T fp16)
  f16* y16    = qk16;                             // alias: qk16 dead after phi

  prep_kernel<<<2592, 256, 0, stream>>>(x, omega, x16, omT16, vT16);
  tr_both_kernel<<<4096, 256, 0, stream>>>(W_attn, W_proj, B16, B16p);
  gemm_qkv_kernel<<<dim3(48, 16), 256, 0, stream>>>(x16, B16, b_attn, qk16, vT16);
  phi_kernel<<<dim3(32, 16, 2), 256, 0, stream>>>(qk16, omT16, phi_q, phi_k, phi_kT);
  chunk_sum_kernel<<<512, 256, 0, stream>>>(vT16, phi_kT, ST);
  prefix_kernel<<<dim3(32, 5), 256, 0, stream>>>(ST);
  intra_kernel<<<512, 256, 0, stream>>>(phi_q, phi_k, vT16, ST, y16);
  gemm_out_kernel<<<dim3(16, 32), 256, 0, stream>>>(y16, B16p, b_proj, out);
}

// Round 6
// 80.027 us; speedup vs baseline: 4.9455x; 1.1051x over previous
//
#include <hip/hip_runtime.h>
#include <math.h>

#define B_ 2
#define T_ 1024
#define C_ 1024
#define NH 16
#define DH 64
#define M_ 128
#define LCH 64
#define NC (T_/LCH)          // 16 chunks
#define DEXT 80              // 64 d + den-row(64) + pad

constexpr float SCALE = 0.125f;              // 1/sqrt(64)
constexpr float EPSV = 1e-6f;
constexpr float INV_SQRT_M = 0.088388347648318447f;  // 1/sqrt(128)

typedef _Float16 f16;
typedef f16 f16x4 __attribute__((ext_vector_type(4)));
typedef f16 f16x8 __attribute__((ext_vector_type(8)));
typedef float f32x4 __attribute__((ext_vector_type(4)));

typedef const __attribute__((address_space(1))) void* as1_cvoid_p;
typedef __attribute__((address_space(3))) void* as3_void_p;

__device__ __forceinline__ void gload16(const void* g, void* l) {
  __builtin_amdgcn_global_load_lds((as1_cvoid_p)g, (as3_void_p)l, 16, 0, 0);
}

// swizzled element index: row of (slots*8) f16, 16B-slot XOR'd by low row bits
__device__ __forceinline__ int sw4(int row, int slot)  { return row * 32  + ((slot ^ (row & 3))  << 3); }
__device__ __forceinline__ int sw8(int row, int slot)  { return row * 64  + ((slot ^ (row & 7))  << 3); }
__device__ __forceinline__ int sw16(int row, int slot) { return row * 128 + ((slot ^ (row & 15)) << 3); }

// ---------- prep: x->fp16, omega transpose, vT den-rows init, both weight transposes ----------
__global__ __launch_bounds__(256) void prep_kernel(const float* __restrict__ x,
                                                   const float* __restrict__ omega,
                                                   const float* __restrict__ Wa,
                                                   const float* __restrict__ Wp,
                                                   f16* __restrict__ x16,
                                                   f16* __restrict__ omT,
                                                   f16* __restrict__ vT,
                                                   f16* __restrict__ B16,
                                                   f16* __restrict__ B16p) {
  __shared__ float tile[32][33];
  int bid = blockIdx.x, tid = threadIdx.x;
  if (bid < 2048) {
    int i = (bid * 256 + tid) * 4;
    float4 v = *(const float4*)&x[i];
    f16x4 o = {(f16)v.x, (f16)v.y, (f16)v.z, (f16)v.w};
    *(f16x4*)&x16[i] = o;
  } else if (bid < 2080) {
    int e = (bid - 2048) * 256 + tid;
    int d = e >> 7, m = e & 127;
    omT[m * 64 + d] = (f16)omega[e];
  } else if (bid < 2592) {
    int idx = bid - 2080;             // 0..511
    int bh = idx >> 4, dr = idx & 15;
    f16 val = (dr == 0) ? (f16)1.0f : (f16)0.0f;
    f16x4 o = {val, val, val, val};
    *(f16x4*)&vT[((size_t)bh * DEXT + 64 + dr) * 1024 + tid * 4] = o;
  } else {
    int tb = bid - 2592;
    const float* in; f16* out; int N, n0, k0;
    if (tb < 3072) { in = Wa; out = B16;  N = 3072; n0 = (tb % 96) * 32; k0 = (tb / 96) * 32; }
    else { tb -= 3072; in = Wp; out = B16p; N = 1024; n0 = (tb & 31) * 32; k0 = (tb >> 5) * 32; }
    int tx = tid & 31, ty = tid >> 5;
    for (int r = ty; r < 32; r += 8)
      tile[r][tx] = in[(size_t)(k0 + r) * N + n0 + tx];
    __syncthreads();
    for (int r = ty; r < 32; r += 8)
      out[(size_t)(n0 + r) * 1024 + k0 + tx] = (f16)tile[tx][r];
  }
}

// ---------- qkv GEMM (fp16 MFMA, dbuf prefetch): qk16 [row][2048], vT16 [bh][d][t] ------------
__global__ __launch_bounds__(256) void gemm_qkv_kernel(
    const f16* __restrict__ A, const f16* __restrict__ B,
    const float* __restrict__ bias, f16* __restrict__ qk16, f16* __restrict__ vT16) {
  __shared__ f16 As[2][128 * 32];
  __shared__ f16 Bs[2][64 * 32];
  const int tid = threadIdx.x;
  const int wid = tid >> 6, lane = tid & 63;
  const int bm = blockIdx.y * 128, bn = blockIdx.x * 64;
  const int wr = (wid >> 1) * 64, wc = (wid & 1) * 32;
  const int sr = wid * 16 + (lane >> 2);
  const int sk = ((lane & 3) ^ (sr & 3)) * 8;      // pre-swizzled source chunk
  const int frow = lane & 15, fkc = lane >> 4;
  f32x4 acc[4][2];
#pragma unroll
  for (int mi = 0; mi < 4; ++mi)
#pragma unroll
    for (int ni = 0; ni < 2; ++ni) acc[mi][ni] = f32x4{0.f, 0.f, 0.f, 0.f};

  auto STAGE = [&](int buf, int kt) {
#pragma unroll
    for (int i = 0; i < 2; ++i)
      gload16(&A[(size_t)(bm + i * 64 + sr) * 1024 + kt + sk],
              (char*)As[buf] + i * 4096 + wid * 1024);
    gload16(&B[(size_t)(bn + sr) * 1024 + kt + sk], (char*)Bs[buf] + wid * 1024);
  };
  STAGE(0, 0);
  for (int kt = 0; kt < 1024; kt += 32) {
    const int cur = (kt >> 5) & 1;
    if (kt + 32 < 1024) {
      STAGE(cur ^ 1, kt + 32);
      asm volatile("s_waitcnt vmcnt(3)" ::: "memory");
    } else {
      asm volatile("s_waitcnt vmcnt(0)" ::: "memory");
    }
    __builtin_amdgcn_s_barrier();
    asm volatile("" ::: "memory");
    f16x8 af[4], bf[2];
#pragma unroll
    for (int mi = 0; mi < 4; ++mi)
      af[mi] = *(const f16x8*)&As[cur][sw4(wr + mi * 16 + frow, fkc)];
#pragma unroll
    for (int ni = 0; ni < 2; ++ni)
      bf[ni] = *(const f16x8*)&Bs[cur][sw4(wc + ni * 16 + frow, fkc)];
#pragma unroll
    for (int mi = 0; mi < 4; ++mi)
#pragma unroll
      for (int ni = 0; ni < 2; ++ni)
        acc[mi][ni] = __builtin_amdgcn_mfma_f32_16x16x32_f16(af[mi], bf[ni], acc[mi][ni], 0, 0, 0);
    asm volatile("" ::: "memory");
    __builtin_amdgcn_s_barrier();
  }
#pragma unroll
  for (int ni = 0; ni < 2; ++ni) {
    int col = bn + wc + ni * 16 + frow;
    float bv = bias[col];
#pragma unroll
    for (int mi = 0; mi < 4; ++mi) {
      int row0 = bm + wr + mi * 16 + (lane >> 4) * 4;
#pragma unroll
      for (int r = 0; r < 4; ++r) {
        int row = row0 + r;
        f16 hv = (f16)(acc[mi][ni][r] + bv);
        if (col < 2048) {
          qk16[(size_t)row * 2048 + col] = hv;
        } else {
          int cc = col - 2048, hh = cc >> 6, d = cc & 63;
          int b = row >> 10, t = row & 1023;
          vT16[((size_t)(b * 16 + hh) * DEXT + d) * 1024 + t] = hv;
        }
      }
    }
  }
}

// ---------- final proj GEMM (fp16 MFMA, 128x64 tile, dbuf prefetch) -> f32 out ----------------
__global__ __launch_bounds__(256) void gemm_out_kernel(
    const f16* __restrict__ A, const f16* __restrict__ B,
    const float* __restrict__ bias, float* __restrict__ C) {
  __shared__ f16 As[2][128 * 32];
  __shared__ f16 Bs[2][64 * 32];
  const int tid = threadIdx.x;
  const int wid = tid >> 6, lane = tid & 63;
  const int bm = blockIdx.y * 128, bn = blockIdx.x * 64;
  const int wr = (wid >> 1) * 64, wc = (wid & 1) * 32;
  const int sr = wid * 16 + (lane >> 2);
  const int sk = ((lane & 3) ^ (sr & 3)) * 8;
  const int frow = lane & 15, fkc = lane >> 4;
  f32x4 acc[4][2];
#pragma unroll
  for (int mi = 0; mi < 4; ++mi)
#pragma unroll
    for (int ni = 0; ni < 2; ++ni) acc[mi][ni] = f32x4{0.f, 0.f, 0.f, 0.f};

  auto STAGE = [&](int buf, int kt) {
#pragma unroll
    for (int i = 0; i < 2; ++i)
      gload16(&A[(size_t)(bm + i * 64 + sr) * 1024 + kt + sk],
              (char*)As[buf] + i * 4096 + wid * 1024);
    gload16(&B[(size_t)(bn + sr) * 1024 + kt + sk], (char*)Bs[buf] + wid * 1024);
  };
  STAGE(0, 0);
  for (int kt = 0; kt < 1024; kt += 32) {
    const int cur = (kt >> 5) & 1;
    if (kt + 32 < 1024) {
      STAGE(cur ^ 1, kt + 32);
      asm volatile("s_waitcnt vmcnt(3)" ::: "memory");
    } else {
      asm volatile("s_waitcnt vmcnt(0)" ::: "memory");
    }
    __builtin_amdgcn_s_barrier();
    asm volatile("" ::: "memory");
    f16x8 af[4], bf[2];
#pragma unroll
    for (int mi = 0; mi < 4; ++mi)
      af[mi] = *(const f16x8*)&As[cur][sw4(wr + mi * 16 + frow, fkc)];
#pragma unroll
    for (int ni = 0; ni < 2; ++ni)
      bf[ni] = *(const f16x8*)&Bs[cur][sw4(wc + ni * 16 + frow, fkc)];
#pragma unroll
    for (int mi = 0; mi < 4; ++mi)
#pragma unroll
      for (int ni = 0; ni < 2; ++ni)
        acc[mi][ni] = __builtin_amdgcn_mfma_f32_16x16x32_f16(af[mi], bf[ni], acc[mi][ni], 0, 0, 0);
    asm volatile("" ::: "memory");
    __builtin_amdgcn_s_barrier();
  }
#pragma unroll
  for (int ni = 0; ni < 2; ++ni) {
    int col = bn + wc + ni * 16 + frow;
    float bv = bias[col];
#pragma unroll
    for (int mi = 0; mi < 4; ++mi) {
      int row0 = bm + wr + mi * 16 + (lane >> 4) * 4;
#pragma unroll
      for (int r = 0; r < 4; ++r)
        C[(size_t)(row0 + r) * 1024 + col] = acc[mi][ni][r] + bv;
    }
  }
}

// ---------- chunkS: recompute phi_k for chunk, then ST[d'][m] = vT_ext @ phi_k ----------------
__global__ __launch_bounds__(256) void chunkS_kernel(const f16* __restrict__ qk16,
                                                     const f16* __restrict__ omT,
                                                     const f16* __restrict__ vT,
                                                     f16* __restrict__ ST) {
  __shared__ f16 om_s[8192];    // [128 m][64 d] sw8
  __shared__ f16 k_s[4096];     // [64 t][64 d] sw8
  __shared__ f16 pkT_s[8192];   // [128 m][64 t] sw8
  __shared__ f16 vt_s[5120];    // [80 d'][64 t] sw8
  __shared__ float nsq_s[64];
  const int tid = threadIdx.x;
  const int wid = tid >> 6, lane = tid & 63;
  const int bc = blockIdx.x;
  const int bh = bc / NC, c = bc % NC;
  const int b = bh >> 4, h = bh & 15;
  const int tbase = c * LCH;
  const int frow = lane & 15, fkc = lane >> 4;
#pragma unroll
  for (int r = 0; r < 4; ++r) {
    int row = r * 32 + wid * 8 + (lane >> 3);
    gload16(omT + row * 64 + ((lane & 7) ^ (row & 7)) * 8,
            (char*)om_s + r * 4096 + wid * 1024);
  }
  {
    int rbase = b * 1024 + tbase, cbase = 1024 + h * 64;
#pragma unroll
    for (int r = 0; r < 2; ++r) {
      int row = r * 32 + wid * 8 + (lane >> 3);
      gload16(qk16 + (size_t)(rbase + row) * 2048 + cbase + ((lane & 7) ^ (row & 7)) * 8,
              (char*)k_s + r * 4096 + wid * 1024);
    }
  }
  for (int rr = wid; rr < 10; rr += 4) {
    int d = rr * 8 + (lane >> 3);
    gload16(vT + ((size_t)bh * DEXT + d) * 1024 + tbase + ((lane & 7) ^ (d & 7)) * 8,
            (char*)vt_s + rr * 1024);
  }
  __syncthreads();
  if (tid < 64) {
    float s = 0.f;
#pragma unroll
    for (int j = 0; j < 8; ++j) {
      f16x8 v = *(const f16x8*)&k_s[sw8(tid, j)];
#pragma unroll
      for (int e = 0; e < 8; ++e) { float f = (float)v[e]; s += f * f; }
    }
    nsq_s[tid] = s;
  }
  // phi_k: C[t][m] = k @ omT^T (A = k rows t, B = om rows m)
  f32x4 acc2[8];
#pragma unroll
  for (int cm = 0; cm < 8; ++cm) acc2[cm] = f32x4{0.f, 0.f, 0.f, 0.f};
  {
    f16x8 af2[2], bf2;
#pragma unroll
    for (int kk = 0; kk < 2; ++kk)
      af2[kk] = *(const f16x8*)&k_s[sw8(wid * 16 + frow, kk * 4 + fkc)];
#pragma unroll
    for (int cm = 0; cm < 8; ++cm)
#pragma unroll
      for (int kk = 0; kk < 2; ++kk) {
        bf2 = *(const f16x8*)&om_s[sw8(cm * 16 + frow, kk * 4 + fkc)];
        acc2[cm] = __builtin_amdgcn_mfma_f32_16x16x32_f16(af2[kk], bf2, acc2[cm], 0, 0, 0);
      }
  }
  __syncthreads();
  const float c2 = -0.5f * SCALE * SCALE;
  {
    int t0g = wid * 16 + (lane >> 4) * 4;
    int slot = t0g >> 3, sub = t0g & 4;
    float4 n4 = *(float4*)&nsq_s[t0g];
    float nn[4] = {c2 * n4.x, c2 * n4.y, c2 * n4.z, c2 * n4.w};
#pragma unroll
    for (int cm = 0; cm < 8; ++cm) {
      int m = cm * 16 + frow;
      f16x4 o;
#pragma unroll
      for (int r = 0; r < 4; ++r)
        o[r] = (f16)(__expf(SCALE * acc2[cm][r] + nn[r]) * INV_SQRT_M);
      *(f16x4*)&pkT_s[m * 64 + ((slot ^ (m & 7)) << 3) + sub] = o;
    }
  }
  __syncthreads();
  // ST MFMA: acc[5][2] = vt_s (A rows d') x pkT_s (B rows m)
  f32x4 acc[5][2];
#pragma unroll
  for (int dt = 0; dt < 5; ++dt)
#pragma unroll
    for (int cj = 0; cj < 2; ++cj) acc[dt][cj] = f32x4{0.f, 0.f, 0.f, 0.f};
  f16x8 af, bf[2][2];
#pragma unroll
  for (int cj = 0; cj < 2; ++cj)
#pragma unroll
    for (int kk = 0; kk < 2; ++kk)
      bf[cj][kk] = *(const f16x8*)&pkT_s[sw8(wid * 32 + cj * 16 + frow, kk * 4 + fkc)];
#pragma unroll
  for (int dt = 0; dt < 5; ++dt)
#pragma unroll
    for (int kk = 0; kk < 2; ++kk) {
      af = *(const f16x8*)&vt_s[sw8(dt * 16 + frow, kk * 4 + fkc)];
#pragma unroll
      for (int cj = 0; cj < 2; ++cj)
        acc[dt][cj] = __builtin_amdgcn_mfma_f32_16x16x32_f16(af, bf[cj][kk], acc[dt][cj], 0, 0, 0);
    }
  f16* dst = ST + (size_t)bc * (DEXT * 128);
#pragma unroll
  for (int dt = 0; dt < 5; ++dt)
#pragma unroll
    for (int cj = 0; cj < 2; ++cj) {
      int m = wid * 32 + cj * 16 + frow;
      int d0 = dt * 16 + (lane >> 4) * 4;
#pragma unroll
      for (int r = 0; r < 4; ++r)
        dst[(size_t)(d0 + r) * 128 + m] = (f16)acc[dt][cj][r];
    }
}

// ---------- exclusive prefix over chunks, in place (fp16, f32 accum) --------------------------
__global__ __launch_bounds__(256) void prefix_kernel(f16* __restrict__ ST) {
  int tid = threadIdx.x;
  int bh = blockIdx.x;
  int d = blockIdx.y * 16 + (tid >> 4), m0 = (tid & 15) * 8;
  float run[8] = {};
  for (int c = 0; c < NC; ++c) {
    f16* p = ST + ((size_t)(bh * NC + c) * DEXT + d) * 128 + m0;
    f16x8 v = *(f16x8*)p;
    f16x8 o;
#pragma unroll
    for (int j = 0; j < 8; ++j) {
      o[j] = (f16)run[j];
      run[j] += (float)v[j];
    }
    *(f16x8*)p = o;
  }
}

// ---------- intra: recompute phi_q/phi_k, QK^T -> causal A -> y = (A@Vext + phiq@SText)/den ---
__global__ __launch_bounds__(256) void intra_kernel(const f16* __restrict__ qk16,
    const f16* __restrict__ omT, const f16* __restrict__ vT,
    const f16* __restrict__ ST, f16* __restrict__ y16) {
  __shared__ f16 pq_s[8192];    // [64 t][128 m] sw16
  __shared__ f16 pk_s[8192];    // [64 t][128 m] sw16
  __shared__ f16 vt_s[5120];    // [80 d'][64 t] sw8
  __shared__ f16 r2[16384];     // phase A: om(0..8191) q(8192..12287) k(12288..16383)
                                // phase B: st(0..10239) a(10240..14335)
  __shared__ float nsq_s[128];  // [0..63]=q, [64..127]=k
  __shared__ float den_s[64];
  f16* om_s = r2;
  f16* q_s  = r2 + 8192;
  f16* k_s  = r2 + 12288;
  f16* st_s = r2;
  f16* a_s  = r2 + 10240;
  const int tid = threadIdx.x;
  const int wid = tid >> 6, lane = tid & 63;
  const int bc = blockIdx.x;
  const int bh = bc / NC, c = bc % NC;
  const int b = bh >> 4, h = bh & 15;
  const int tbase = c * LCH;
  const int frow = lane & 15, fkc = lane >> 4;
  // ---- stage om, q, k, vt ----
#pragma unroll
  for (int r = 0; r < 4; ++r) {
    int row = r * 32 + wid * 8 + (lane >> 3);
    gload16(omT + row * 64 + ((lane & 7) ^ (row & 7)) * 8,
            (char*)om_s + r * 4096 + wid * 1024);
  }
  {
    int rbase = b * 1024 + tbase;
#pragma unroll
    for (int r = 0; r < 2; ++r) {
      int row = r * 32 + wid * 8 + (lane >> 3);
      int csw = ((lane & 7) ^ (row & 7)) * 8;
      gload16(qk16 + (size_t)(rbase + row) * 2048 + h * 64 + csw,
              (char*)q_s + r * 4096 + wid * 1024);
      gload16(qk16 + (size_t)(rbase + row) * 2048 + 1024 + h * 64 + csw,
              (char*)k_s + r * 4096 + wid * 1024);
    }
  }
  for (int rr = wid; rr < 10; rr += 4) {
    int d = rr * 8 + (lane >> 3);
    gload16(vT + ((size_t)bh * DEXT + d) * 1024 + tbase + ((lane & 7) ^ (d & 7)) * 8,
            (char*)vt_s + rr * 1024);
  }
  __syncthreads();
  // ---- nsq for q and k rows ----
  if (tid < 128) {
    const f16* src = (tid < 64) ? q_s : k_s;
    int t = tid & 63;
    float s = 0.f;
#pragma unroll
    for (int j = 0; j < 8; ++j) {
      f16x8 v = *(const f16x8*)&src[sw8(t, j)];
#pragma unroll
      for (int e = 0; e < 8; ++e) { float f = (float)v[e]; s += f * f; }
    }
    nsq_s[tid] = s;
  }
  // ---- phi MFMAs: C[m][t] = omT @ {q,k}^T ----
  f32x4 acc1q[2][4], acc1k[2][4];
#pragma unroll
  for (int mi = 0; mi < 2; ++mi)
#pragma unroll
    for (int ct = 0; ct < 4; ++ct) {
      acc1q[mi][ct] = f32x4{0.f, 0.f, 0.f, 0.f};
      acc1k[mi][ct] = f32x4{0.f, 0.f, 0.f, 0.f};
    }
  {
    f16x8 af[2][2], bfq, bfk;
#pragma unroll
    for (int mi = 0; mi < 2; ++mi)
#pragma unroll
      for (int kk = 0; kk < 2; ++kk)
        af[mi][kk] = *(const f16x8*)&om_s[sw8(wid * 32 + mi * 16 + frow, kk * 4 + fkc)];
#pragma unroll
    for (int ct = 0; ct < 4; ++ct)
#pragma unroll
      for (int kk = 0; kk < 2; ++kk) {
        bfq = *(const f16x8*)&q_s[sw8(ct * 16 + frow, kk * 4 + fkc)];
        bfk = *(const f16x8*)&k_s[sw8(ct * 16 + frow, kk * 4 + fkc)];
#pragma unroll
        for (int mi = 0; mi < 2; ++mi) {
          acc1q[mi][ct] = __builtin_amdgcn_mfma_f32_16x16x32_f16(af[mi][kk], bfq, acc1q[mi][ct], 0, 0, 0);
          acc1k[mi][ct] = __builtin_amdgcn_mfma_f32_16x16x32_f16(af[mi][kk], bfk, acc1k[mi][ct], 0, 0, 0);
        }
      }
  }
  __syncthreads();
  // ---- exp + write pq_s, pk_s [t][128] sw16 (om/q/k now dead) ----
  const float c2 = -0.5f * SCALE * SCALE;
#pragma unroll
  for (int ct = 0; ct < 4; ++ct) {
    int t = ct * 16 + frow;
    float nq = c2 * nsq_s[t], nk = c2 * nsq_s[64 + t];
#pragma unroll
    for (int mi = 0; mi < 2; ++mi) {
      int m0 = wid * 32 + mi * 16 + (lane >> 4) * 4;
      int addr = t * 128 + (((m0 >> 3) ^ (t & 15)) << 3) + (m0 & 4);
      f16x4 oq, ok;
#pragma unroll
      for (int r = 0; r < 4; ++r) {
        oq[r] = (f16)(__expf(SCALE * acc1q[mi][ct][r] + nq) * INV_SQRT_M);
        ok[r] = (f16)(__expf(SCALE * acc1k[mi][ct][r] + nk) * INV_SQRT_M);
      }
      *(f16x4*)&pq_s[addr] = oq;
      *(f16x4*)&pk_s[addr] = ok;
    }
  }
  __syncthreads();
  // ---- issue ST gloads into r2[0..10240) (lands during QK^T) ----
#pragma unroll
  for (int r = 0; r < 5; ++r) {
    int row = r * 16 + wid * 4 + (lane >> 4);
    int col = ((lane & 15) ^ (row & 15)) * 8;
    gload16(ST + (size_t)bc * (DEXT * 128) + (size_t)row * 128 + col,
            (char*)st_s + r * 4096 + wid * 1024);
  }
  // ---- QK^T swapped: A = pk rows tk, B = pq cols tq -> C'[tk][tq]; causal A_s[tq][tk] sw8 ----
  {
    f32x4 accq[4];
#pragma unroll
    for (int ct = 0; ct < 4; ++ct) accq[ct] = f32x4{0.f, 0.f, 0.f, 0.f};
    f16x8 af[4], bf;
#pragma unroll
    for (int kk = 0; kk < 4; ++kk)
      af[kk] = *(const f16x8*)&pk_s[sw16(wid * 16 + frow, kk * 4 + fkc)];
#pragma unroll
    for (int ct = 0; ct < 4; ++ct)
#pragma unroll
      for (int kk = 0; kk < 4; ++kk) {
        bf = *(const f16x8*)&pq_s[sw16(ct * 16 + frow, kk * 4 + fkc)];
        accq[ct] = __builtin_amdgcn_mfma_f32_16x16x32_f16(af[kk], bf, accq[ct], 0, 0, 0);
      }
    int tkbase = wid * 16 + fkc * 4;
    int slot = tkbase >> 3, sub = tkbase & 4;
#pragma unroll
    for (int ct = 0; ct < 4; ++ct) {
      int tq = ct * 16 + frow;
      f16x4 av;
#pragma unroll
      for (int r = 0; r < 4; ++r)
        av[r] = (f16)((tkbase + r <= tq) ? accq[ct][r] : 0.f);
      *(f16x4*)&a_s[tq * 64 + ((slot ^ (tq & 7)) << 3) + sub] = av;
    }
  }
  asm volatile("s_waitcnt vmcnt(0)" ::: "memory");
  __syncthreads();
  // ---- phase 2: y_ext[ti][d'] = A @ vT_ext + phi_q @ ST_ext  (col 64 = den) ----
  f32x4 acc2[5];
#pragma unroll
  for (int ct = 0; ct < 5; ++ct) acc2[ct] = f32x4{0.f, 0.f, 0.f, 0.f};
  {
    f16x8 afA[2], afP[4], bfv;
#pragma unroll
    for (int kk = 0; kk < 2; ++kk)
      afA[kk] = *(const f16x8*)&a_s[sw8(wid * 16 + frow, kk * 4 + fkc)];
#pragma unroll
    for (int kk = 0; kk < 4; ++kk)
      afP[kk] = *(const f16x8*)&pq_s[sw16(wid * 16 + frow, kk * 4 + fkc)];
#pragma unroll
    for (int ct = 0; ct < 5; ++ct) {
#pragma unroll
      for (int kk = 0; kk < 2; ++kk) {
        bfv = *(const f16x8*)&vt_s[sw8(ct * 16 + frow, kk * 4 + fkc)];
        acc2[ct] = __builtin_amdgcn_mfma_f32_16x16x32_f16(afA[kk], bfv, acc2[ct], 0, 0, 0);
      }
#pragma unroll
      for (int kk = 0; kk < 4; ++kk) {
        bfv = *(const f16x8*)&st_s[sw16(ct * 16 + frow, kk * 4 + fkc)];
        acc2[ct] = __builtin_amdgcn_mfma_f32_16x16x32_f16(afP[kk], bfv, acc2[ct], 0, 0, 0);
      }
    }
  }
  if (frow == 0) {
    int t0g = wid * 16 + (lane >> 4) * 4;
#pragma unroll
    for (int r = 0; r < 4; ++r) den_s[t0g + r] = acc2[4][r];
  }
  __syncthreads();
  {
    int t0g = wid * 16 + (lane >> 4) * 4;
    float4 d4 = *(float4*)&den_s[t0g];
    float inv[4] = {1.f / (d4.x + EPSV), 1.f / (d4.y + EPSV),
                    1.f / (d4.z + EPSV), 1.f / (d4.w + EPSV)};
#pragma unroll
    for (int ct = 0; ct < 4; ++ct) {
      int d = ct * 16 + frow;
#pragma unroll
      for (int r = 0; r < 4; ++r) {
        int t = t0g + r;
        y16[(size_t)(b * 1024 + tbase + t) * 1024 + h * 64 + d] =
            (f16)(acc2[ct][r] * inv[r]);
      }
    }
  }
}

extern "C" void kernel_launch(void* const* d_in, const int* in_sizes, int n_in,
                              void* d_out, int out_size, void* d_ws, size_t ws_size,
                              hipStream_t stream) {
  const float* x      = (const float*)d_in[0];
  const float* W_attn = (const float*)d_in[1];
  const float* b_attn = (const float*)d_in[2];
  const float* W_proj = (const float*)d_in[3];
  const float* b_proj = (const float*)d_in[4];
  const float* omega  = (const float*)d_in[5];
  float* out = (float*)d_out;

  char* base = (char*)d_ws;
  f16* x16    = (f16*)(base);                     // 4,194,304 B
  f16* B16    = (f16*)(base + 4194304);           // 6,291,456 B (W_attn^T fp16)
  f16* qk16   = (f16*)(base + 10485760);          // 8,388,608 B  [y16 aliases]
  f16* vT16   = (f16*)(base + 18874368);          // 5,242,880 B  [80 x 1024 per bh]
  f16* ST     = (f16*)(base + 24117248);          // 10,485,760 B [512 x 80 x 128]
  f16* omT16  = (f16*)(base + 34603008);          // 16,384 B
  f16* B16p   = (f16*)(base + 34619392);          // 2,097,152 B (W_proj^T fp16)
  f16* y16    = qk16;                             // alias: qk16 dead after intra reads it...
                                                  // NOTE: intra reads qk16 and writes y16 to
                                                  // DIFFERENT element ranges? No — same rows.
                                                  // Safe because y16 writes land only in the
                                                  // q-half columns? No. Use separate buffer:
  y16 = (f16*)(base + 36716544);                  // 4,194,304 B

  prep_kernel<<<6688, 256, 0, stream>>>(x, omega, W_attn, W_proj, x16, omT16, vT16, B16, B16p);
  gemm_qkv_kernel<<<dim3(48, 16), 256, 0, stream>>>(x16, B16, b_attn, qk16, vT16);
  chunkS_kernel<<<512, 256, 0, stream>>>(qk16, omT16, vT16, ST);
  prefix_kernel<<<dim3(32, 5), 256, 0, stream>>>(ST);
  intra_kernel<<<512, 256, 0, stream>>>(qk16, omT16, vT16, ST, y16);
  gemm_out_kernel<<<dim3(16, 16), 256, 0, stream>>>(y16, B16p, b_proj, out);
}